// Round 1
// baseline (1380.609 us; speedup 1.0000x reference)
//
#include <hip/hip_runtime.h>
#include <math.h>

#define F_IN 3
#define CH 32
#define HEADS 4
#define C1_OUT 64
#define C2_OUT 128
#define LIN 256
#define NCLS 25

__device__ __forceinline__ float elu_f(float x) {
    return x > 0.f ? x : (__expf(x) - 1.f);
}

__device__ __forceinline__ float sel4(int h, float a, float b, float c, float d) {
    return h == 0 ? a : (h == 1 ? b : (h == 2 ? c : d));
}

__device__ __forceinline__ void softmax4(const float* __restrict__ c,
                                         float& q0, float& q1, float& q2, float& q3) {
    float c0 = c[0], c1 = c[1], c2 = c[2], c3 = c[3];
    float mx = fmaxf(fmaxf(c0, c1), fmaxf(c2, c3));
    float e0 = __expf(c0 - mx), e1 = __expf(c1 - mx);
    float e2 = __expf(c2 - mx), e3 = __expf(c3 - mx);
    float inv = 1.f / (e0 + e1 + e2 + e3);
    q0 = e0 * inv; q1 = e1 * inv; q2 = e2 * inv; q3 = e3 * inv;
}

// ---------------- fc0: h0 = elu(x @ W + b), also cnt[n] = 1 (self-loop) ----
__global__ void k_fc0(const float* __restrict__ x, const float* __restrict__ w,
                      const float* __restrict__ b, float* __restrict__ h0,
                      float* __restrict__ cnt, int n_nodes) {
    int gid = blockIdx.x * blockDim.x + threadIdx.x;
    if (gid >= n_nodes * CH) return;
    int n = gid >> 5, c = gid & 31;
    float acc = b[c];
#pragma unroll
    for (int i = 0; i < F_IN; ++i) acc += x[n * F_IN + i] * w[i * CH + c];
    h0[gid] = elu_f(acc);
    if (c == 0) cnt[n] = 1.0f;
}

// ---------------- degree count over real edges ----------------------------
__global__ void k_count(const int* __restrict__ dst, float* __restrict__ cnt, int ne) {
    int e = blockIdx.x * blockDim.x + threadIdx.x;
    if (e < ne) atomicAdd(&cnt[dst[e]], 1.0f);
}

// ---------------- conv1 edge scatter: 32 lanes per edge, in=32 ------------
__global__ void k_edge1(const float* __restrict__ h, const int* __restrict__ eidx,
                        const float* __restrict__ u, const float* __restrict__ cvec,
                        float* __restrict__ acc, int ne) {
    int gid = blockIdx.x * blockDim.x + threadIdx.x;
    int e = gid >> 5;
    if (e >= ne) return;
    int l = gid & 31;
    int s = eidx[e], d = eidx[ne + e];
    float xj = h[s * CH + l];
    float xi = h[d * CH + l];
    float diff = xj - xi;
    float t0, t1, t2, t3;
    {
        float p0 = diff * u[l * HEADS + 0];
        float p1 = diff * u[l * HEADS + 1];
        float p2 = diff * u[l * HEADS + 2];
        float p3 = diff * u[l * HEADS + 3];
#pragma unroll
        for (int m = 16; m >= 1; m >>= 1) {
            p0 += __shfl_xor(p0, m, 32);
            p1 += __shfl_xor(p1, m, 32);
            p2 += __shfl_xor(p2, m, 32);
            p3 += __shfl_xor(p3, m, 32);
        }
        t0 = p0 + cvec[0]; t1 = p1 + cvec[1]; t2 = p2 + cvec[2]; t3 = p3 + cvec[3];
    }
    float mx = fmaxf(fmaxf(t0, t1), fmaxf(t2, t3));
    float q0 = __expf(t0 - mx), q1 = __expf(t1 - mx);
    float q2 = __expf(t2 - mx), q3 = __expf(t3 - mx);
    float inv = 1.f / (q0 + q1 + q2 + q3);
    float base = xj * inv;
    atomicAdd(&acc[d * (HEADS * CH) + 0 * CH + l], q0 * base);
    atomicAdd(&acc[d * (HEADS * CH) + 1 * CH + l], q1 * base);
    atomicAdd(&acc[d * (HEADS * CH) + 2 * CH + l], q2 * base);
    atomicAdd(&acc[d * (HEADS * CH) + 3 * CH + l], q3 * base);
}

// ---------------- conv2 edge scatter: 64 lanes per edge, in=64 ------------
__global__ void k_edge2(const float* __restrict__ h, const int* __restrict__ eidx,
                        const float* __restrict__ u, const float* __restrict__ cvec,
                        float* __restrict__ acc, int ne) {
    int gid = blockIdx.x * blockDim.x + threadIdx.x;
    int e = gid >> 6;
    if (e >= ne) return;
    int l = gid & 63;
    int s = eidx[e], d = eidx[ne + e];
    float xj = h[s * C1_OUT + l];
    float xi = h[d * C1_OUT + l];
    float diff = xj - xi;
    float t0, t1, t2, t3;
    {
        float p0 = diff * u[l * HEADS + 0];
        float p1 = diff * u[l * HEADS + 1];
        float p2 = diff * u[l * HEADS + 2];
        float p3 = diff * u[l * HEADS + 3];
#pragma unroll
        for (int m = 32; m >= 1; m >>= 1) {
            p0 += __shfl_xor(p0, m, 64);
            p1 += __shfl_xor(p1, m, 64);
            p2 += __shfl_xor(p2, m, 64);
            p3 += __shfl_xor(p3, m, 64);
        }
        t0 = p0 + cvec[0]; t1 = p1 + cvec[1]; t2 = p2 + cvec[2]; t3 = p3 + cvec[3];
    }
    float mx = fmaxf(fmaxf(t0, t1), fmaxf(t2, t3));
    float q0 = __expf(t0 - mx), q1 = __expf(t1 - mx);
    float q2 = __expf(t2 - mx), q3 = __expf(t3 - mx);
    float inv = 1.f / (q0 + q1 + q2 + q3);
    float base = xj * inv;
    atomicAdd(&acc[d * (HEADS * C1_OUT) + 0 * C1_OUT + l], q0 * base);
    atomicAdd(&acc[d * (HEADS * C1_OUT) + 1 * C1_OUT + l], q1 * base);
    atomicAdd(&acc[d * (HEADS * C1_OUT) + 2 * C1_OUT + l], q2 * base);
    atomicAdd(&acc[d * (HEADS * C1_OUT) + 3 * C1_OUT + l], q3 * base);
}

// ---------------- conv1 node GEMM: h1 = elu((acc/cnt) @ Wr + b) -----------
// arow length 128 (H*32), out 64. 4 nodes / block of 256.
__global__ __launch_bounds__(256) void k_gemm1(
    const float* __restrict__ accin, const float* __restrict__ h0,
    const float* __restrict__ cnt, const float* __restrict__ W,
    const float* __restrict__ cvec, const float* __restrict__ bias,
    float* __restrict__ out, int n_nodes) {
    __shared__ float Wl[128 * 64];   // 32 KB
    __shared__ float arow[4][128];   // 2 KB
    int tid = threadIdx.x;
    int n0 = blockIdx.x * 4;
    float qc0, qc1, qc2, qc3;
    softmax4(cvec, qc0, qc1, qc2, qc3);
    for (int idx = tid; idx < 128 * 64; idx += 256) {
        int j = idx >> 6, o = idx & 63;
        int hh = j >> 5, k = j & 31;
        Wl[idx] = W[k * (HEADS * C1_OUT) + hh * C1_OUT + o];
    }
    for (int idx = tid; idx < 4 * 128; idx += 256) {
        int ln = idx >> 7, j = idx & 127;
        int node = n0 + ln;
        float v = 0.f;
        if (node < n_nodes) {
            int hh = j >> 5, k = j & 31;
            float qch = sel4(hh, qc0, qc1, qc2, qc3);
            v = (accin[node * 128 + j] + qch * h0[node * CH + k]) / cnt[node];
        }
        arow[ln][j] = v;
    }
    __syncthreads();
    int ln = tid >> 6, o = tid & 63;
    int node = n0 + ln;
    float s = bias[o];
#pragma unroll
    for (int j = 0; j < 128; ++j) s += arow[ln][j] * Wl[j * 64 + o];
    if (node < n_nodes) out[node * C1_OUT + o] = elu_f(s);
}

// ---------------- conv2 node GEMM: arow 256, out 128, 8 nodes / block -----
__global__ __launch_bounds__(256) void k_gemm2(
    const float* __restrict__ accin, const float* __restrict__ h1,
    const float* __restrict__ cnt, const float* __restrict__ W,
    const float* __restrict__ cvec, const float* __restrict__ bias,
    float* __restrict__ out, int n_nodes) {
    __shared__ float Wl[64 * 128];   // 32 KB
    __shared__ float arow[8][256];   // 8 KB
    int tid = threadIdx.x;
    int n0 = blockIdx.x * 8;
    float qc0, qc1, qc2, qc3;
    softmax4(cvec, qc0, qc1, qc2, qc3);
    for (int idx = tid; idx < 8 * 256; idx += 256) {
        int ln = idx >> 8, j = idx & 255;
        int node = n0 + ln;
        float v = 0.f;
        if (node < n_nodes) {
            int hh = j >> 6, k = j & 63;
            float qch = sel4(hh, qc0, qc1, qc2, qc3);
            v = (accin[node * 256 + j] + qch * h1[node * C1_OUT + k]) / cnt[node];
        }
        arow[ln][j] = v;
    }
    int o = tid & 127, s0 = tid >> 7;
    float a0 = 0.f, a1 = 0.f, a2 = 0.f, a3 = 0.f;
    for (int cch = 0; cch < 4; ++cch) {
        __syncthreads();
        for (int idx = tid; idx < 64 * 128; idx += 256) {
            int jj = idx >> 7, oo = idx & 127;
            int j = cch * 64 + jj;
            int hh = j >> 6, k = j & 63;
            Wl[idx] = W[k * (HEADS * C2_OUT) + hh * C2_OUT + oo];
        }
        __syncthreads();
#pragma unroll
        for (int jj = 0; jj < 64; ++jj) {
            float wv = Wl[jj * 128 + o];
            a0 += arow[s0 + 0][cch * 64 + jj] * wv;
            a1 += arow[s0 + 2][cch * 64 + jj] * wv;
            a2 += arow[s0 + 4][cch * 64 + jj] * wv;
            a3 += arow[s0 + 6][cch * 64 + jj] * wv;
        }
    }
    float b = bias[o];
    int n;
    n = n0 + s0 + 0; if (n < n_nodes) out[n * C2_OUT + o] = elu_f(a0 + b);
    n = n0 + s0 + 2; if (n < n_nodes) out[n * C2_OUT + o] = elu_f(a1 + b);
    n = n0 + s0 + 4; if (n < n_nodes) out[n * C2_OUT + o] = elu_f(a2 + b);
    n = n0 + s0 + 6; if (n < n_nodes) out[n * C2_OUT + o] = elu_f(a3 + b);
}

// ---------------- fc1: h3 = elu(h2 @ W + b), in 128, out 256 --------------
__global__ __launch_bounds__(256) void k_fc1(
    const float* __restrict__ h2, const float* __restrict__ W,
    const float* __restrict__ bias, float* __restrict__ out, int n_nodes) {
    __shared__ float Wl[32 * 256];   // 32 KB
    __shared__ float xrow[8][128];   // 4 KB
    int tid = threadIdx.x;
    int n0 = blockIdx.x * 8;
    for (int idx = tid; idx < 8 * 128; idx += 256) {
        int ln = idx >> 7, k = idx & 127;
        int node = n0 + ln;
        xrow[ln][k] = (node < n_nodes) ? h2[node * C2_OUT + k] : 0.f;
    }
    float a[8] = {0.f, 0.f, 0.f, 0.f, 0.f, 0.f, 0.f, 0.f};
    int o = tid;
    for (int cch = 0; cch < 4; ++cch) {
        __syncthreads();
        for (int idx = tid; idx < 32 * 256; idx += 256) {
            int kk = idx >> 8, oo = idx & 255;
            Wl[idx] = W[(cch * 32 + kk) * LIN + oo];
        }
        __syncthreads();
#pragma unroll
        for (int kk = 0; kk < 32; ++kk) {
            float wv = Wl[kk * 256 + o];
#pragma unroll
            for (int ss = 0; ss < 8; ++ss)
                a[ss] += xrow[ss][cch * 32 + kk] * wv;
        }
    }
    float b = bias[o];
#pragma unroll
    for (int ss = 0; ss < 8; ++ss) {
        int node = n0 + ss;
        if (node < n_nodes) out[node * LIN + o] = elu_f(a[ss] + b);
    }
}

// ---------------- fc2 + log_softmax: one thread per node ------------------
__global__ void k_fc2(const float* __restrict__ h3, const float* __restrict__ W,
                      const float* __restrict__ bias, float* __restrict__ out,
                      int n_nodes) {
    int n = blockIdx.x * blockDim.x + threadIdx.x;
    if (n >= n_nodes) return;
    float acc[NCLS];
#pragma unroll
    for (int o = 0; o < NCLS; ++o) acc[o] = bias[o];
    const float* xr = h3 + (size_t)n * LIN;
    for (int k = 0; k < LIN; ++k) {
        float v = xr[k];
#pragma unroll
        for (int o = 0; o < NCLS; ++o) acc[o] += v * W[k * NCLS + o];
    }
    float mx = acc[0];
#pragma unroll
    for (int o = 1; o < NCLS; ++o) mx = fmaxf(mx, acc[o]);
    float sum = 0.f;
#pragma unroll
    for (int o = 0; o < NCLS; ++o) sum += __expf(acc[o] - mx);
    float lse = mx + __logf(sum);
#pragma unroll
    for (int o = 0; o < NCLS; ++o) out[(size_t)n * NCLS + o] = acc[o] - lse;
}

extern "C" void kernel_launch(void* const* d_in, const int* in_sizes, int n_in,
                              void* d_out, int out_size, void* d_ws, size_t ws_size,
                              hipStream_t stream) {
    const float* x     = (const float*)d_in[0];
    const int*   eidx  = (const int*)d_in[1];
    const float* fc0_w = (const float*)d_in[2];
    const float* fc0_b = (const float*)d_in[3];
    const float* c1w   = (const float*)d_in[4];
    const float* c1u   = (const float*)d_in[5];
    const float* c1c   = (const float*)d_in[6];
    const float* c1b   = (const float*)d_in[7];
    const float* c2w   = (const float*)d_in[8];
    const float* c2u   = (const float*)d_in[9];
    const float* c2c   = (const float*)d_in[10];
    const float* c2b   = (const float*)d_in[11];
    const float* fc1w  = (const float*)d_in[12];
    const float* fc1b  = (const float*)d_in[13];
    const float* fc2w  = (const float*)d_in[14];
    const float* fc2b  = (const float*)d_in[15];

    int n_nodes = in_sizes[0] / F_IN;   // 50000
    int ne      = in_sizes[1] / 2;      // 800000

    float* ws   = (float*)d_ws;
    float* cnt  = ws;
    float* h0   = cnt + n_nodes;
    float* acc1 = h0 + (size_t)n_nodes * CH;
    float* h1   = acc1 + (size_t)n_nodes * (HEADS * CH);
    float* acc2 = h1 + (size_t)n_nodes * C1_OUT;
    float* h2   = acc1;   // reuse: acc1 dead after gemm1
    float* h3   = acc2;   // reuse: acc2 dead after gemm2
    float* out  = (float*)d_out;

    hipMemsetAsync(acc1, 0, (size_t)n_nodes * (HEADS * CH) * sizeof(float), stream);
    hipMemsetAsync(acc2, 0, (size_t)n_nodes * (HEADS * C1_OUT) * sizeof(float), stream);

    k_fc0<<<(n_nodes * CH + 255) / 256, 256, 0, stream>>>(x, fc0_w, fc0_b, h0, cnt, n_nodes);
    k_count<<<(ne + 255) / 256, 256, 0, stream>>>(eidx + ne, cnt, ne);
    k_edge1<<<(ne * 32 + 255) / 256, 256, 0, stream>>>(h0, eidx, c1u, c1c, acc1, ne);
    k_gemm1<<<(n_nodes + 3) / 4, 256, 0, stream>>>(acc1, h0, cnt, c1w, c1c, c1b, h1, n_nodes);
    k_edge2<<<(ne * 64 + 255) / 256, 256, 0, stream>>>(h1, eidx, c2u, c2c, acc2, ne);
    k_gemm2<<<(n_nodes + 7) / 8, 256, 0, stream>>>(acc2, h1, cnt, c2w, c2c, c2b, h2, n_nodes);
    k_fc1<<<(n_nodes + 7) / 8, 256, 0, stream>>>(h2, fc1w, fc1b, h3, n_nodes);
    k_fc2<<<(n_nodes + 255) / 256, 256, 0, stream>>>(h3, fc2w, fc2b, out, n_nodes);
}

// Round 2
// 599.924 us; speedup vs baseline: 2.3013x; 2.3013x over previous
//
#include <hip/hip_runtime.h>
#include <math.h>

#define F_IN 3
#define CH 32
#define HEADS 4
#define C1_OUT 64
#define C2_OUT 128
#define LIN 256
#define NCLS 25

__device__ __forceinline__ float elu_f(float x) {
    return x > 0.f ? x : (__expf(x) - 1.f);
}

__device__ __forceinline__ void softmax4(const float* __restrict__ c,
                                         float& q0, float& q1, float& q2, float& q3) {
    float c0 = c[0], c1 = c[1], c2 = c[2], c3 = c[3];
    float mx = fmaxf(fmaxf(c0, c1), fmaxf(c2, c3));
    float e0 = __expf(c0 - mx), e1 = __expf(c1 - mx);
    float e2 = __expf(c2 - mx), e3 = __expf(c3 - mx);
    float inv = 1.f / (e0 + e1 + e2 + e3);
    q0 = e0 * inv; q1 = e1 * inv; q2 = e2 * inv; q3 = e3 * inv;
}

// ---------------- fc0: h0 = elu(x @ W + b) ---------------------------------
__global__ void k_fc0(const float* __restrict__ x, const float* __restrict__ w,
                      const float* __restrict__ b, float* __restrict__ h0,
                      int n_nodes) {
    int gid = blockIdx.x * blockDim.x + threadIdx.x;
    if (gid >= n_nodes * CH) return;
    int n = gid >> 5, c = gid & 31;
    float acc = b[c];
#pragma unroll
    for (int i = 0; i < F_IN; ++i) acc += x[n * F_IN + i] * w[i * CH + c];
    h0[gid] = elu_f(acc);
}

// ---------------- degree count (into cur, used as deg) ---------------------
__global__ void k_deg(const int* __restrict__ dst, int* __restrict__ deg, int ne) {
    int e = blockIdx.x * blockDim.x + threadIdx.x;
    if (e < ne) atomicAdd(&deg[dst[e]], 1);
}

// ---------------- two-level exclusive scan ---------------------------------
#define SCAN_BS 1024
__global__ __launch_bounds__(SCAN_BS) void k_scan_a(
    const int* __restrict__ deg, int* __restrict__ offa,
    int* __restrict__ blksum, int n) {
    __shared__ int buf[SCAN_BS];
    int tid = threadIdx.x;
    int i = blockIdx.x * SCAN_BS + tid;
    int v = (i < n) ? deg[i] : 0;
    buf[tid] = v;
    __syncthreads();
    for (int s = 1; s < SCAN_BS; s <<= 1) {
        int t = (tid >= s) ? buf[tid - s] : 0;
        __syncthreads();
        buf[tid] += t;
        __syncthreads();
    }
    if (i < n) offa[i] = buf[tid] - v;            // local exclusive
    if (tid == SCAN_BS - 1) blksum[blockIdx.x] = buf[tid];
}

__global__ void k_scan_b(int* __restrict__ blksum, int* __restrict__ offa,
                         int nblk, int n) {
    int tid = threadIdx.x;   // single wave of 64, nblk <= 64
    int orig = (tid < nblk) ? blksum[tid] : 0;
    int v = orig;
#pragma unroll
    for (int s = 1; s < 64; s <<= 1) {
        int t = __shfl_up(v, s, 64);
        if (tid >= s) v += t;
    }
    if (tid < nblk) blksum[tid] = v - orig;       // exclusive block offsets
    if (tid == nblk - 1) offa[n] = v;             // total = ne
}

__global__ void k_scan_c(int* __restrict__ offa, int* __restrict__ cur,
                         const int* __restrict__ blksum, int n) {
    int i = blockIdx.x * blockDim.x + threadIdx.x;
    if (i < n) {
        int o = offa[i] + blksum[i >> 10];
        offa[i] = o;
        cur[i] = o;
    }
}

// ---------------- scatter edges into dst-sorted order ----------------------
__global__ void k_scatter(const int* __restrict__ eidx, int* __restrict__ cur,
                          int* __restrict__ ssrc, int* __restrict__ sdst, int ne) {
    int e = blockIdx.x * blockDim.x + threadIdx.x;
    if (e >= ne) return;
    int s = eidx[e], d = eidx[ne + e];
    int pos = atomicAdd(&cur[d], 1);
    ssrc[pos] = s;
    sdst[pos] = d;
}

// ---------------- per-node head projection p[n,h] = h[n] . u_h -------------
template<int IN>
__global__ void k_proj(const float* __restrict__ h, const float* __restrict__ u,
                       float* __restrict__ p, int n_nodes) {
    int node = blockIdx.x * blockDim.x + threadIdx.x;
    if (node >= n_nodes) return;
    const float* hr = h + (size_t)node * IN;
    float a0 = 0.f, a1 = 0.f, a2 = 0.f, a3 = 0.f;
#pragma unroll
    for (int k = 0; k < IN; ++k) {
        float v = hr[k];
        a0 = fmaf(v, u[k * HEADS + 0], a0);
        a1 = fmaf(v, u[k * HEADS + 1], a1);
        a2 = fmaf(v, u[k * HEADS + 2], a2);
        a3 = fmaf(v, u[k * HEADS + 3], a3);
    }
    p[node * 4 + 0] = a0; p[node * 4 + 1] = a1;
    p[node * 4 + 2] = a2; p[node * 4 + 3] = a3;
}

// ---------------- per-edge attention weights (sorted order) ----------------
__global__ void k_q(const float* __restrict__ p, const float* __restrict__ cvec,
                    const int* __restrict__ ssrc, const int* __restrict__ sdst,
                    float4* __restrict__ q4, int ne) {
    int e = blockIdx.x * blockDim.x + threadIdx.x;
    if (e >= ne) return;
    int s = ssrc[e], d = sdst[e];
    float t0 = p[s * 4 + 0] - p[d * 4 + 0] + cvec[0];
    float t1 = p[s * 4 + 1] - p[d * 4 + 1] + cvec[1];
    float t2 = p[s * 4 + 2] - p[d * 4 + 2] + cvec[2];
    float t3 = p[s * 4 + 3] - p[d * 4 + 3] + cvec[3];
    float mx = fmaxf(fmaxf(t0, t1), fmaxf(t2, t3));
    float e0 = __expf(t0 - mx), e1 = __expf(t1 - mx);
    float e2 = __expf(t2 - mx), e3 = __expf(t3 - mx);
    float inv = 1.f / (e0 + e1 + e2 + e3);
    q4[e] = make_float4(e0 * inv, e1 * inv, e2 * inv, e3 * inv);
}

// ---------------- conv1 gather-aggregate: wave/node, 32ch half-split -------
__global__ __launch_bounds__(256) void k_agg1(
    const float* __restrict__ h, const int* __restrict__ offa,
    const int* __restrict__ ssrc, const float4* __restrict__ q4,
    const float* __restrict__ cvec, float* __restrict__ arow, int n_nodes) {
    int wid = (blockIdx.x * blockDim.x + threadIdx.x) >> 6;
    int lane = threadIdx.x & 63;
    if (wid >= n_nodes) return;
    int half = lane >> 5, k = lane & 31;
    int e0 = offa[wid], e1 = offa[wid + 1];
    float a0 = 0.f, a1 = 0.f, a2 = 0.f, a3 = 0.f;
    for (int e = e0 + half; e < e1; e += 2) {
        int s = ssrc[e];
        float4 q = q4[e];
        float xj = h[(size_t)s * CH + k];
        a0 = fmaf(q.x, xj, a0); a1 = fmaf(q.y, xj, a1);
        a2 = fmaf(q.z, xj, a2); a3 = fmaf(q.w, xj, a3);
    }
    a0 += __shfl_xor(a0, 32); a1 += __shfl_xor(a1, 32);
    a2 += __shfl_xor(a2, 32); a3 += __shfl_xor(a3, 32);
    if (half == 0) {
        float qc0, qc1, qc2, qc3;
        softmax4(cvec, qc0, qc1, qc2, qc3);
        float xi = h[(size_t)wid * CH + k];
        a0 = fmaf(qc0, xi, a0); a1 = fmaf(qc1, xi, a1);
        a2 = fmaf(qc2, xi, a2); a3 = fmaf(qc3, xi, a3);
        float inv = 1.f / (float)(e1 - e0 + 1);
        arow[(size_t)wid * 128 + 0 * CH + k] = a0 * inv;
        arow[(size_t)wid * 128 + 1 * CH + k] = a1 * inv;
        arow[(size_t)wid * 128 + 2 * CH + k] = a2 * inv;
        arow[(size_t)wid * 128 + 3 * CH + k] = a3 * inv;
    }
}

// ---------------- conv2 gather-aggregate: wave/node, 64 channels -----------
__global__ __launch_bounds__(256) void k_agg2(
    const float* __restrict__ h, const int* __restrict__ offa,
    const int* __restrict__ ssrc, const float4* __restrict__ q4,
    const float* __restrict__ cvec, float* __restrict__ arow, int n_nodes) {
    int wid = (blockIdx.x * blockDim.x + threadIdx.x) >> 6;
    int lane = threadIdx.x & 63;
    if (wid >= n_nodes) return;
    int e0 = offa[wid], e1 = offa[wid + 1];
    float a0 = 0.f, a1 = 0.f, a2 = 0.f, a3 = 0.f;
    for (int e = e0; e < e1; ++e) {
        int s = ssrc[e];
        float4 q = q4[e];
        float xj = h[(size_t)s * C1_OUT + lane];
        a0 = fmaf(q.x, xj, a0); a1 = fmaf(q.y, xj, a1);
        a2 = fmaf(q.z, xj, a2); a3 = fmaf(q.w, xj, a3);
    }
    float qc0, qc1, qc2, qc3;
    softmax4(cvec, qc0, qc1, qc2, qc3);
    float xi = h[(size_t)wid * C1_OUT + lane];
    a0 = fmaf(qc0, xi, a0); a1 = fmaf(qc1, xi, a1);
    a2 = fmaf(qc2, xi, a2); a3 = fmaf(qc3, xi, a3);
    float inv = 1.f / (float)(e1 - e0 + 1);
    arow[(size_t)wid * 256 + 0 * C1_OUT + lane] = a0 * inv;
    arow[(size_t)wid * 256 + 1 * C1_OUT + lane] = a1 * inv;
    arow[(size_t)wid * 256 + 2 * C1_OUT + lane] = a2 * inv;
    arow[(size_t)wid * 256 + 3 * C1_OUT + lane] = a3 * inv;
}

// ---------------- conv1 node GEMM: h1 = elu(arow @ Wr + b) ------------------
__global__ __launch_bounds__(256) void k_gemm1(
    const float* __restrict__ arowg, const float* __restrict__ W,
    const float* __restrict__ bias, float* __restrict__ out, int n_nodes) {
    __shared__ float Wl[128 * 64];   // 32 KB
    __shared__ float arow[4][128];
    int tid = threadIdx.x;
    int n0 = blockIdx.x * 4;
    for (int idx = tid; idx < 128 * 64; idx += 256) {
        int j = idx >> 6, o = idx & 63;
        int hh = j >> 5, k = j & 31;
        Wl[idx] = W[k * (HEADS * C1_OUT) + hh * C1_OUT + o];
    }
    for (int idx = tid; idx < 4 * 128; idx += 256) {
        int ln = idx >> 7, j = idx & 127;
        int node = n0 + ln;
        arow[ln][j] = (node < n_nodes) ? arowg[(size_t)node * 128 + j] : 0.f;
    }
    __syncthreads();
    int ln = tid >> 6, o = tid & 63;
    int node = n0 + ln;
    float s = bias[o];
#pragma unroll
    for (int j = 0; j < 128; ++j) s += arow[ln][j] * Wl[j * 64 + o];
    if (node < n_nodes) out[(size_t)node * C1_OUT + o] = elu_f(s);
}

// ---------------- conv2 node GEMM: h2 = elu(arow @ Wr + b) ------------------
__global__ __launch_bounds__(256) void k_gemm2(
    const float* __restrict__ arowg, const float* __restrict__ W,
    const float* __restrict__ bias, float* __restrict__ out, int n_nodes) {
    __shared__ float Wl[64 * 128];   // 32 KB
    __shared__ float arow[8][256];
    int tid = threadIdx.x;
    int n0 = blockIdx.x * 8;
    for (int idx = tid; idx < 8 * 256; idx += 256) {
        int ln = idx >> 8, j = idx & 255;
        int node = n0 + ln;
        arow[ln][j] = (node < n_nodes) ? arowg[(size_t)node * 256 + j] : 0.f;
    }
    int o = tid & 127, s0 = tid >> 7;
    float a0 = 0.f, a1 = 0.f, a2 = 0.f, a3 = 0.f;
    for (int cch = 0; cch < 4; ++cch) {
        __syncthreads();
        for (int idx = tid; idx < 64 * 128; idx += 256) {
            int jj = idx >> 7, oo = idx & 127;
            int j = cch * 64 + jj;
            int hh = j >> 6, k = j & 63;
            Wl[idx] = W[k * (HEADS * C2_OUT) + hh * C2_OUT + oo];
        }
        __syncthreads();
#pragma unroll
        for (int jj = 0; jj < 64; ++jj) {
            float wv = Wl[jj * 128 + o];
            a0 += arow[s0 + 0][cch * 64 + jj] * wv;
            a1 += arow[s0 + 2][cch * 64 + jj] * wv;
            a2 += arow[s0 + 4][cch * 64 + jj] * wv;
            a3 += arow[s0 + 6][cch * 64 + jj] * wv;
        }
    }
    float b = bias[o];
    int n;
    n = n0 + s0 + 0; if (n < n_nodes) out[(size_t)n * C2_OUT + o] = elu_f(a0 + b);
    n = n0 + s0 + 2; if (n < n_nodes) out[(size_t)n * C2_OUT + o] = elu_f(a1 + b);
    n = n0 + s0 + 4; if (n < n_nodes) out[(size_t)n * C2_OUT + o] = elu_f(a2 + b);
    n = n0 + s0 + 6; if (n < n_nodes) out[(size_t)n * C2_OUT + o] = elu_f(a3 + b);
}

// ---------------- fc1: h3 = elu(h2 @ W + b), in 128, out 256 ----------------
__global__ __launch_bounds__(256) void k_fc1(
    const float* __restrict__ h2, const float* __restrict__ W,
    const float* __restrict__ bias, float* __restrict__ out, int n_nodes) {
    __shared__ float Wl[32 * 256];   // 32 KB
    __shared__ float xrow[8][128];
    int tid = threadIdx.x;
    int n0 = blockIdx.x * 8;
    for (int idx = tid; idx < 8 * 128; idx += 256) {
        int ln = idx >> 7, k = idx & 127;
        int node = n0 + ln;
        xrow[ln][k] = (node < n_nodes) ? h2[(size_t)node * C2_OUT + k] : 0.f;
    }
    float a[8] = {0.f, 0.f, 0.f, 0.f, 0.f, 0.f, 0.f, 0.f};
    int o = tid;
    for (int cch = 0; cch < 4; ++cch) {
        __syncthreads();
        for (int idx = tid; idx < 32 * 256; idx += 256) {
            int kk = idx >> 8, oo = idx & 255;
            Wl[idx] = W[(cch * 32 + kk) * LIN + oo];
        }
        __syncthreads();
#pragma unroll
        for (int kk = 0; kk < 32; ++kk) {
            float wv = Wl[kk * 256 + o];
#pragma unroll
            for (int ss = 0; ss < 8; ++ss)
                a[ss] += xrow[ss][cch * 32 + kk] * wv;
        }
    }
    float b = bias[o];
#pragma unroll
    for (int ss = 0; ss < 8; ++ss) {
        int node = n0 + ss;
        if (node < n_nodes) out[(size_t)node * LIN + o] = elu_f(a[ss] + b);
    }
}

// ---------------- fc2 + log_softmax: one thread per node -------------------
__global__ void k_fc2(const float* __restrict__ h3, const float* __restrict__ W,
                      const float* __restrict__ bias, float* __restrict__ out,
                      int n_nodes) {
    int n = blockIdx.x * blockDim.x + threadIdx.x;
    if (n >= n_nodes) return;
    float acc[NCLS];
#pragma unroll
    for (int o = 0; o < NCLS; ++o) acc[o] = bias[o];
    const float* xr = h3 + (size_t)n * LIN;
    for (int k = 0; k < LIN; ++k) {
        float v = xr[k];
#pragma unroll
        for (int o = 0; o < NCLS; ++o) acc[o] = fmaf(v, W[k * NCLS + o], acc[o]);
    }
    float mx = acc[0];
#pragma unroll
    for (int o = 1; o < NCLS; ++o) mx = fmaxf(mx, acc[o]);
    float sum = 0.f;
#pragma unroll
    for (int o = 0; o < NCLS; ++o) sum += __expf(acc[o] - mx);
    float lse = mx + __logf(sum);
#pragma unroll
    for (int o = 0; o < NCLS; ++o) out[(size_t)n * NCLS + o] = acc[o] - lse;
}

extern "C" void kernel_launch(void* const* d_in, const int* in_sizes, int n_in,
                              void* d_out, int out_size, void* d_ws, size_t ws_size,
                              hipStream_t stream) {
    const float* x     = (const float*)d_in[0];
    const int*   eidx  = (const int*)d_in[1];
    const float* fc0_w = (const float*)d_in[2];
    const float* fc0_b = (const float*)d_in[3];
    const float* c1w   = (const float*)d_in[4];
    const float* c1u   = (const float*)d_in[5];
    const float* c1c   = (const float*)d_in[6];
    const float* c1b   = (const float*)d_in[7];
    const float* c2w   = (const float*)d_in[8];
    const float* c2u   = (const float*)d_in[9];
    const float* c2c   = (const float*)d_in[10];
    const float* c2b   = (const float*)d_in[11];
    const float* fc1w  = (const float*)d_in[12];
    const float* fc1b  = (const float*)d_in[13];
    const float* fc2w  = (const float*)d_in[14];
    const float* fc2b  = (const float*)d_in[15];

    int n_nodes = in_sizes[0] / F_IN;   // 50000
    int ne      = in_sizes[1] / 2;      // 800000

    // ---- workspace layout (element units of 4 B), liveness-aliased ----
    auto align4 = [](size_t v) { return (v + 3) & ~(size_t)3; };
    float* ws = (float*)d_ws;
    size_t t = 0;
    size_t off_o = t; t += align4((size_t)n_nodes + 1);
    size_t cur_o = t; t += align4((size_t)n_nodes);
    size_t blk_o = t; t += 64;
    size_t p_o   = t; t += align4((size_t)n_nodes * 4);
    size_t h1_o  = t; t += (size_t)n_nodes * 64;
    size_t A_o   = t; t += (size_t)n_nodes * 256;  // arow1 | arow2 | h3
    size_t B_o   = t;                              // {h0, ssrc, sdst, q4} | h2
    size_t h0_o  = B_o;
    size_t ss_o  = h0_o + (size_t)n_nodes * CH;
    size_t sd_o  = align4(ss_o + (size_t)ne);
    size_t q4_o  = align4(sd_o + (size_t)ne);

    int*    offa   = (int*)(ws + off_o);
    int*    cur    = (int*)(ws + cur_o);
    int*    blksum = (int*)(ws + blk_o);
    float*  p      = ws + p_o;
    float*  h1     = ws + h1_o;
    float*  arow1  = ws + A_o;   // n*128 used
    float*  arow2  = ws + A_o;   // n*256
    float*  h3     = ws + A_o;   // n*256
    float*  h0     = ws + h0_o;
    int*    ssrc   = (int*)(ws + ss_o);
    int*    sdst   = (int*)(ws + sd_o);
    float4* q4     = (float4*)(ws + q4_o);
    float*  h2     = ws + B_o;   // n*128, after {h0,ssrc,sdst,q4} are dead
    float*  out    = (float*)d_out;

    int nblk = (n_nodes + SCAN_BS - 1) / SCAN_BS;   // 49 <= 64

    // deg counting uses `cur` as the counter array
    hipMemsetAsync(cur, 0, (size_t)n_nodes * sizeof(int), stream);

    k_fc0<<<(n_nodes * CH + 255) / 256, 256, 0, stream>>>(x, fc0_w, fc0_b, h0, n_nodes);
    k_deg<<<(ne + 255) / 256, 256, 0, stream>>>(eidx + ne, cur, ne);
    k_scan_a<<<nblk, SCAN_BS, 0, stream>>>(cur, offa, blksum, n_nodes);
    k_scan_b<<<1, 64, 0, stream>>>(blksum, offa, nblk, n_nodes);
    k_scan_c<<<(n_nodes + 255) / 256, 256, 0, stream>>>(offa, cur, blksum, n_nodes);
    k_scatter<<<(ne + 255) / 256, 256, 0, stream>>>(eidx, cur, ssrc, sdst, ne);

    // conv1
    k_proj<CH><<<(n_nodes + 255) / 256, 256, 0, stream>>>(h0, c1u, p, n_nodes);
    k_q<<<(ne + 255) / 256, 256, 0, stream>>>(p, c1c, ssrc, sdst, q4, ne);
    k_agg1<<<(n_nodes * 64 + 255) / 256, 256, 0, stream>>>(h0, offa, ssrc, q4, c1c, arow1, n_nodes);
    k_gemm1<<<(n_nodes + 3) / 4, 256, 0, stream>>>(arow1, c1w, c1b, h1, n_nodes);

    // conv2
    k_proj<C1_OUT><<<(n_nodes + 255) / 256, 256, 0, stream>>>(h1, c2u, p, n_nodes);
    k_q<<<(ne + 255) / 256, 256, 0, stream>>>(p, c2c, ssrc, sdst, q4, ne);
    k_agg2<<<(n_nodes * 64 + 255) / 256, 256, 0, stream>>>(h1, offa, ssrc, q4, c2c, arow2, n_nodes);
    k_gemm2<<<(n_nodes + 7) / 8, 256, 0, stream>>>(arow2, c2w, c2b, h2, n_nodes);

    // head
    k_fc1<<<(n_nodes + 7) / 8, 256, 0, stream>>>(h2, fc1w, fc1b, h3, n_nodes);
    k_fc2<<<(n_nodes + 255) / 256, 256, 0, stream>>>(h3, fc2w, fc2b, out, n_nodes);
}

// Round 3
// 370.635 us; speedup vs baseline: 3.7250x; 1.6186x over previous
//
#include <hip/hip_runtime.h>
#include <math.h>

#define F_IN 3
#define CH 32
#define HEADS 4
#define C1_OUT 64
#define C2_OUT 128
#define LIN 256
#define NCLS 25

typedef __attribute__((ext_vector_type(8))) short bf16x8;
typedef __attribute__((ext_vector_type(4))) float f32x4;

__device__ __forceinline__ float elu_f(float x) {
    return x > 0.f ? x : (__expf(x) - 1.f);
}

__device__ __forceinline__ unsigned short f2bf(float f) {
    union { float f; unsigned int u; } v; v.f = f;
    unsigned int u = v.u + 0x7fffu + ((v.u >> 16) & 1u);
    return (unsigned short)(u >> 16);
}

__device__ __forceinline__ void softmax4(const float* __restrict__ c,
                                         float& q0, float& q1, float& q2, float& q3) {
    float c0 = c[0], c1 = c[1], c2 = c[2], c3 = c[3];
    float mx = fmaxf(fmaxf(c0, c1), fmaxf(c2, c3));
    float e0 = __expf(c0 - mx), e1 = __expf(c1 - mx);
    float e2 = __expf(c2 - mx), e3 = __expf(c3 - mx);
    float inv = 1.f / (e0 + e1 + e2 + e3);
    q0 = e0 * inv; q1 = e1 * inv; q2 = e2 * inv; q3 = e3 * inv;
}

// ---------------- fc0: h0 = elu(x @ W + b) ---------------------------------
__global__ void k_fc0(const float* __restrict__ x, const float* __restrict__ w,
                      const float* __restrict__ b, float* __restrict__ h0,
                      int n_nodes) {
    int gid = blockIdx.x * blockDim.x + threadIdx.x;
    if (gid >= n_nodes * CH) return;
    int n = gid >> 5, c = gid & 31;
    float acc = b[c];
#pragma unroll
    for (int i = 0; i < F_IN; ++i) acc += x[n * F_IN + i] * w[i * CH + c];
    h0[gid] = elu_f(acc);
}

// ---------------- degree count (into cur, used as deg) ---------------------
__global__ void k_deg(const int* __restrict__ dst, int* __restrict__ deg, int ne) {
    int e = blockIdx.x * blockDim.x + threadIdx.x;
    if (e < ne) atomicAdd(&deg[dst[e]], 1);
}

// ---------------- two-level exclusive scan ---------------------------------
#define SCAN_BS 1024
__global__ __launch_bounds__(SCAN_BS) void k_scan_a(
    const int* __restrict__ deg, int* __restrict__ offa,
    int* __restrict__ blksum, int n) {
    __shared__ int buf[SCAN_BS];
    int tid = threadIdx.x;
    int i = blockIdx.x * SCAN_BS + tid;
    int v = (i < n) ? deg[i] : 0;
    buf[tid] = v;
    __syncthreads();
    for (int s = 1; s < SCAN_BS; s <<= 1) {
        int t = (tid >= s) ? buf[tid - s] : 0;
        __syncthreads();
        buf[tid] += t;
        __syncthreads();
    }
    if (i < n) offa[i] = buf[tid] - v;            // local exclusive
    if (tid == SCAN_BS - 1) blksum[blockIdx.x] = buf[tid];
}

__global__ void k_scan_b(int* __restrict__ blksum, int* __restrict__ offa,
                         int nblk, int n) {
    int tid = threadIdx.x;   // single wave of 64, nblk <= 64
    int orig = (tid < nblk) ? blksum[tid] : 0;
    int v = orig;
#pragma unroll
    for (int s = 1; s < 64; s <<= 1) {
        int t = __shfl_up(v, s, 64);
        if (tid >= s) v += t;
    }
    if (tid < nblk) blksum[tid] = v - orig;       // exclusive block offsets
    if (tid == nblk - 1) offa[n] = v;             // total = ne
}

__global__ void k_scan_c(int* __restrict__ offa, int* __restrict__ cur,
                         const int* __restrict__ blksum, int n) {
    int i = blockIdx.x * blockDim.x + threadIdx.x;
    if (i < n) {
        int o = offa[i] + blksum[i >> 10];
        offa[i] = o;
        cur[i] = o;
    }
}

// ---------------- scatter edges into dst-sorted order ----------------------
__global__ void k_scatter(const int* __restrict__ eidx, int* __restrict__ cur,
                          int* __restrict__ ssrc, int* __restrict__ sdst, int ne) {
    int e = blockIdx.x * blockDim.x + threadIdx.x;
    if (e >= ne) return;
    int s = eidx[e], d = eidx[ne + e];
    int pos = atomicAdd(&cur[d], 1);
    ssrc[pos] = s;
    sdst[pos] = d;
}

// ---------------- per-node head projection p[n,h] = h[n] . u_h -------------
template<int IN>
__global__ void k_proj(const float* __restrict__ h, const float* __restrict__ u,
                       float* __restrict__ p, int n_nodes) {
    int node = blockIdx.x * blockDim.x + threadIdx.x;
    if (node >= n_nodes) return;
    const float* hr = h + (size_t)node * IN;
    float a0 = 0.f, a1 = 0.f, a2 = 0.f, a3 = 0.f;
#pragma unroll
    for (int k = 0; k < IN; ++k) {
        float v = hr[k];
        a0 = fmaf(v, u[k * HEADS + 0], a0);
        a1 = fmaf(v, u[k * HEADS + 1], a1);
        a2 = fmaf(v, u[k * HEADS + 2], a2);
        a3 = fmaf(v, u[k * HEADS + 3], a3);
    }
    p[node * 4 + 0] = a0; p[node * 4 + 1] = a1;
    p[node * 4 + 2] = a2; p[node * 4 + 3] = a3;
}

// ---------------- per-edge attention weights (sorted order) ----------------
__global__ void k_q(const float* __restrict__ p, const float* __restrict__ cvec,
                    const int* __restrict__ ssrc, const int* __restrict__ sdst,
                    float4* __restrict__ q4, int ne) {
    int e = blockIdx.x * blockDim.x + threadIdx.x;
    if (e >= ne) return;
    int s = ssrc[e], d = sdst[e];
    float t0 = p[s * 4 + 0] - p[d * 4 + 0] + cvec[0];
    float t1 = p[s * 4 + 1] - p[d * 4 + 1] + cvec[1];
    float t2 = p[s * 4 + 2] - p[d * 4 + 2] + cvec[2];
    float t3 = p[s * 4 + 3] - p[d * 4 + 3] + cvec[3];
    float mx = fmaxf(fmaxf(t0, t1), fmaxf(t2, t3));
    float e0 = __expf(t0 - mx), e1 = __expf(t1 - mx);
    float e2 = __expf(t2 - mx), e3 = __expf(t3 - mx);
    float inv = 1.f / (e0 + e1 + e2 + e3);
    q4[e] = make_float4(e0 * inv, e1 * inv, e2 * inv, e3 * inv);
}

// ---------------- conv1 gather-aggregate: wave/node, 32ch half-split -------
__global__ __launch_bounds__(256) void k_agg1(
    const float* __restrict__ h, const int* __restrict__ offa,
    const int* __restrict__ ssrc, const float4* __restrict__ q4,
    const float* __restrict__ cvec, float* __restrict__ arow, int n_nodes) {
    int wid = (blockIdx.x * blockDim.x + threadIdx.x) >> 6;
    int lane = threadIdx.x & 63;
    if (wid >= n_nodes) return;
    int half = lane >> 5, k = lane & 31;
    int e0 = offa[wid], e1 = offa[wid + 1];
    float a0 = 0.f, a1 = 0.f, a2 = 0.f, a3 = 0.f;
    for (int e = e0 + half; e < e1; e += 2) {
        int s = ssrc[e];
        float4 q = q4[e];
        float xj = h[(size_t)s * CH + k];
        a0 = fmaf(q.x, xj, a0); a1 = fmaf(q.y, xj, a1);
        a2 = fmaf(q.z, xj, a2); a3 = fmaf(q.w, xj, a3);
    }
    a0 += __shfl_xor(a0, 32); a1 += __shfl_xor(a1, 32);
    a2 += __shfl_xor(a2, 32); a3 += __shfl_xor(a3, 32);
    if (half == 0) {
        float qc0, qc1, qc2, qc3;
        softmax4(cvec, qc0, qc1, qc2, qc3);
        float xi = h[(size_t)wid * CH + k];
        a0 = fmaf(qc0, xi, a0); a1 = fmaf(qc1, xi, a1);
        a2 = fmaf(qc2, xi, a2); a3 = fmaf(qc3, xi, a3);
        float inv = 1.f / (float)(e1 - e0 + 1);
        arow[(size_t)wid * 128 + 0 * CH + k] = a0 * inv;
        arow[(size_t)wid * 128 + 1 * CH + k] = a1 * inv;
        arow[(size_t)wid * 128 + 2 * CH + k] = a2 * inv;
        arow[(size_t)wid * 128 + 3 * CH + k] = a3 * inv;
    }
}

// ---------------- conv2 gather-aggregate: wave/node, 64 channels -----------
__global__ __launch_bounds__(256) void k_agg2(
    const float* __restrict__ h, const int* __restrict__ offa,
    const int* __restrict__ ssrc, const float4* __restrict__ q4,
    const float* __restrict__ cvec, float* __restrict__ arow, int n_nodes) {
    int wid = (blockIdx.x * blockDim.x + threadIdx.x) >> 6;
    int lane = threadIdx.x & 63;
    if (wid >= n_nodes) return;
    int e0 = offa[wid], e1 = offa[wid + 1];
    float a0 = 0.f, a1 = 0.f, a2 = 0.f, a3 = 0.f;
    for (int e = e0; e < e1; ++e) {
        int s = ssrc[e];
        float4 q = q4[e];
        float xj = h[(size_t)s * C1_OUT + lane];
        a0 = fmaf(q.x, xj, a0); a1 = fmaf(q.y, xj, a1);
        a2 = fmaf(q.z, xj, a2); a3 = fmaf(q.w, xj, a3);
    }
    float qc0, qc1, qc2, qc3;
    softmax4(cvec, qc0, qc1, qc2, qc3);
    float xi = h[(size_t)wid * C1_OUT + lane];
    a0 = fmaf(qc0, xi, a0); a1 = fmaf(qc1, xi, a1);
    a2 = fmaf(qc2, xi, a2); a3 = fmaf(qc3, xi, a3);
    float inv = 1.f / (float)(e1 - e0 + 1);
    arow[(size_t)wid * 256 + 0 * C1_OUT + lane] = a0 * inv;
    arow[(size_t)wid * 256 + 1 * C1_OUT + lane] = a1 * inv;
    arow[(size_t)wid * 256 + 2 * C1_OUT + lane] = a2 * inv;
    arow[(size_t)wid * 256 + 3 * C1_OUT + lane] = a3 * inv;
}

// ---------------- weight prep: Bt[o*K + j] = bf16(remap(W)) ----------------
// IN > 0: FeaStConv remap j = hh*IN + k -> W[k*(HEADS*M) + hh*M + o]
// IN == 0: plain transpose  -> W[j*M + o]
template<int K, int M, int IN>
__global__ void k_prepB(const float* __restrict__ W, unsigned short* __restrict__ Bt) {
    int idx = blockIdx.x * blockDim.x + threadIdx.x;
    if (idx >= K * M) return;
    int o = idx / K, j = idx % K;
    float v;
    if (IN > 0) {
        int hh = j / IN, k = j % IN;
        v = W[k * (HEADS * M) + hh * M + o];
    } else {
        v = W[j * M + o];
    }
    Bt[idx] = f2bf(v);
}

// ---------------- MFMA GEMM: D = elu(A[N,K] @ Bt^T + bias), bf16 inputs ----
// Block: 256 threads = 4 waves; 64 rows per block; wave w owns cols
// [w*M/4, (w+1)*M/4). B frags held in registers, A staged in LDS (swizzled).
template<int K, int M>
__global__ __launch_bounds__(256) void k_mgemm(
    const float* __restrict__ A, const unsigned short* __restrict__ Bt,
    const float* __restrict__ bias, float* __restrict__ D, int n) {
    constexpr int CPW = M / 4;      // cols per wave
    constexpr int NCF = CPW / 16;   // 16-col frags per wave
    constexpr int NKC = K / 32;     // K chunks of 32
    __shared__ unsigned short Al[64 * K];
    int tid = threadIdx.x;
    int w = tid >> 6, l = tid & 63;
    int l16 = l & 15, l4 = l >> 4;   // l4 in [0,4)
    int rowbase = blockIdx.x * 64;

    // B fragments -> registers (bf16): lane holds Bt[col][t*32 + l4*8 .. +7]
    bf16x8 bfr[NCF][NKC];
#pragma unroll
    for (int c = 0; c < NCF; ++c)
#pragma unroll
        for (int t = 0; t < NKC; ++t) {
            int col = w * CPW + c * 16 + l16;
            int k = t * 32 + l4 * 8;
            bfr[c][t] = *(const bf16x8*)(Bt + (size_t)col * K + k);
        }

    // stage A tile: fp32 -> bf16, XOR-swizzled rows (T2: byte ^= (row&7)<<4)
    constexpr int CHUNKS = 64 * K / 8;
    for (int idx = tid; idx < CHUNKS; idx += 256) {
        int row = idx / (K / 8);
        int kb = (idx % (K / 8)) * 8;
        int grow = rowbase + row;
        uint4 u;
        if (grow < n) {
            const float* src = A + (size_t)grow * K + kb;
            float4 x0 = *(const float4*)(src);
            float4 x1 = *(const float4*)(src + 4);
            u.x = (unsigned)f2bf(x0.x) | ((unsigned)f2bf(x0.y) << 16);
            u.y = (unsigned)f2bf(x0.z) | ((unsigned)f2bf(x0.w) << 16);
            u.z = (unsigned)f2bf(x1.x) | ((unsigned)f2bf(x1.y) << 16);
            u.w = (unsigned)f2bf(x1.z) | ((unsigned)f2bf(x1.w) << 16);
        } else {
            u.x = u.y = u.z = u.w = 0u;
        }
        int byte = ((row * K + kb) * 2) ^ ((row & 7) << 4);
        *(uint4*)((char*)Al + byte) = u;
    }
    __syncthreads();

#pragma unroll
    for (int r = 0; r < 4; ++r) {
        // A fragments for row sub-tile r: lane row = r*16 + l16
        bf16x8 af[NKC];
        int row = r * 16 + l16;
#pragma unroll
        for (int t = 0; t < NKC; ++t) {
            int byte = ((row * K + t * 32 + l4 * 8) * 2) ^ ((row & 7) << 4);
            af[t] = *(bf16x8*)((char*)Al + byte);
        }
#pragma unroll
        for (int c = 0; c < NCF; ++c) {
            f32x4 acc = {0.f, 0.f, 0.f, 0.f};
#pragma unroll
            for (int t = 0; t < NKC; ++t)
                acc = __builtin_amdgcn_mfma_f32_16x16x32_bf16(af[t], bfr[c][t], acc, 0, 0, 0);
            int col = w * CPW + c * 16 + l16;
            float bv = bias[col];
#pragma unroll
            for (int j = 0; j < 4; ++j) {
                int grow = rowbase + r * 16 + l4 * 4 + j;
                if (grow < n) {
                    float o = acc[j] + bv;
                    D[(size_t)grow * M + col] = elu_f(o);
                }
            }
        }
    }
}

// ---------------- fc2 + log_softmax: one thread per node -------------------
__global__ void k_fc2(const float* __restrict__ h3, const float* __restrict__ W,
                      const float* __restrict__ bias, float* __restrict__ out,
                      int n_nodes) {
    int n = blockIdx.x * blockDim.x + threadIdx.x;
    if (n >= n_nodes) return;
    float acc[NCLS];
#pragma unroll
    for (int o = 0; o < NCLS; ++o) acc[o] = bias[o];
    const float* xr = h3 + (size_t)n * LIN;
    for (int k = 0; k < LIN; ++k) {
        float v = xr[k];
#pragma unroll
        for (int o = 0; o < NCLS; ++o) acc[o] = fmaf(v, W[k * NCLS + o], acc[o]);
    }
    float mx = acc[0];
#pragma unroll
    for (int o = 1; o < NCLS; ++o) mx = fmaxf(mx, acc[o]);
    float sum = 0.f;
#pragma unroll
    for (int o = 0; o < NCLS; ++o) sum += __expf(acc[o] - mx);
    float lse = mx + __logf(sum);
#pragma unroll
    for (int o = 0; o < NCLS; ++o) out[(size_t)n * NCLS + o] = acc[o] - lse;
}

extern "C" void kernel_launch(void* const* d_in, const int* in_sizes, int n_in,
                              void* d_out, int out_size, void* d_ws, size_t ws_size,
                              hipStream_t stream) {
    const float* x     = (const float*)d_in[0];
    const int*   eidx  = (const int*)d_in[1];
    const float* fc0_w = (const float*)d_in[2];
    const float* fc0_b = (const float*)d_in[3];
    const float* c1w   = (const float*)d_in[4];
    const float* c1u   = (const float*)d_in[5];
    const float* c1c   = (const float*)d_in[6];
    const float* c1b   = (const float*)d_in[7];
    const float* c2w   = (const float*)d_in[8];
    const float* c2u   = (const float*)d_in[9];
    const float* c2c   = (const float*)d_in[10];
    const float* c2b   = (const float*)d_in[11];
    const float* fc1w  = (const float*)d_in[12];
    const float* fc1b  = (const float*)d_in[13];
    const float* fc2w  = (const float*)d_in[14];
    const float* fc2b  = (const float*)d_in[15];

    int n_nodes = in_sizes[0] / F_IN;   // 50000
    int ne      = in_sizes[1] / 2;      // 800000

    // ---- workspace layout (element units of 4 B), liveness-aliased ----
    auto align4 = [](size_t v) { return (v + 3) & ~(size_t)3; };
    float* ws = (float*)d_ws;
    size_t t = 0;
    size_t off_o = t; t += align4((size_t)n_nodes + 1);
    size_t cur_o = t; t += align4((size_t)n_nodes);
    size_t blk_o = t; t += 64;
    size_t p_o   = t; t += align4((size_t)n_nodes * 4);
    size_t h1_o  = t; t += (size_t)n_nodes * 64;
    size_t A_o   = t; t += (size_t)n_nodes * 256;  // arow1 | arow2 | h3
    size_t B_o   = t; t += (size_t)n_nodes * 128;  // {h0, ssrc, sdst, q4} | h2
    size_t bt1_o = t; t += 4096;    // 128*64  bf16
    size_t bt2_o = t; t += 16384;   // 256*128 bf16
    size_t btf_o = t; t += 16384;   // 128*256 bf16

    size_t h0_o  = B_o;
    size_t ss_o  = h0_o + (size_t)n_nodes * CH;
    size_t sd_o  = align4(ss_o + (size_t)ne);
    size_t q4_o  = align4(sd_o + (size_t)ne);

    int*    offa   = (int*)(ws + off_o);
    int*    cur    = (int*)(ws + cur_o);
    int*    blksum = (int*)(ws + blk_o);
    float*  p      = ws + p_o;
    float*  h1     = ws + h1_o;
    float*  arow1  = ws + A_o;   // n*128 used
    float*  arow2  = ws + A_o;   // n*256
    float*  h3     = ws + A_o;   // n*256
    float*  h0     = ws + h0_o;
    int*    ssrc   = (int*)(ws + ss_o);
    int*    sdst   = (int*)(ws + sd_o);
    float4* q4     = (float4*)(ws + q4_o);
    float*  h2     = ws + B_o;   // n*128, after {h0,ssrc,sdst,q4} are dead
    unsigned short* bt1 = (unsigned short*)(ws + bt1_o);
    unsigned short* bt2 = (unsigned short*)(ws + bt2_o);
    unsigned short* btf = (unsigned short*)(ws + btf_o);
    float*  out    = (float*)d_out;

    int nblk = (n_nodes + SCAN_BS - 1) / SCAN_BS;   // 49 <= 64

    hipMemsetAsync(cur, 0, (size_t)n_nodes * sizeof(int), stream);

    // weight prep (tiny)
    k_prepB<128, 64, 32><<<(128 * 64 + 255) / 256, 256, 0, stream>>>(c1w, bt1);
    k_prepB<256, 128, 64><<<(256 * 128 + 255) / 256, 256, 0, stream>>>(c2w, bt2);
    k_prepB<128, 256, 0><<<(128 * 256 + 255) / 256, 256, 0, stream>>>(fc1w, btf);

    k_fc0<<<(n_nodes * CH + 255) / 256, 256, 0, stream>>>(x, fc0_w, fc0_b, h0, n_nodes);
    k_deg<<<(ne + 255) / 256, 256, 0, stream>>>(eidx + ne, cur, ne);
    k_scan_a<<<nblk, SCAN_BS, 0, stream>>>(cur, offa, blksum, n_nodes);
    k_scan_b<<<1, 64, 0, stream>>>(blksum, offa, nblk, n_nodes);
    k_scan_c<<<(n_nodes + 255) / 256, 256, 0, stream>>>(offa, cur, blksum, n_nodes);
    k_scatter<<<(ne + 255) / 256, 256, 0, stream>>>(eidx, cur, ssrc, sdst, ne);

    int ngrid = (n_nodes + 63) / 64;

    // conv1
    k_proj<CH><<<(n_nodes + 255) / 256, 256, 0, stream>>>(h0, c1u, p, n_nodes);
    k_q<<<(ne + 255) / 256, 256, 0, stream>>>(p, c1c, ssrc, sdst, q4, ne);
    k_agg1<<<(n_nodes * 64 + 255) / 256, 256, 0, stream>>>(h0, offa, ssrc, q4, c1c, arow1, n_nodes);
    k_mgemm<128, 64><<<ngrid, 256, 0, stream>>>(arow1, bt1, c1b, h1, n_nodes);

    // conv2
    k_proj<C1_OUT><<<(n_nodes + 255) / 256, 256, 0, stream>>>(h1, c2u, p, n_nodes);
    k_q<<<(ne + 255) / 256, 256, 0, stream>>>(p, c2c, ssrc, sdst, q4, ne);
    k_agg2<<<(n_nodes * 64 + 255) / 256, 256, 0, stream>>>(h1, offa, ssrc, q4, c2c, arow2, n_nodes);
    k_mgemm<256, 128><<<ngrid, 256, 0, stream>>>(arow2, bt2, c2b, h2, n_nodes);

    // head
    k_mgemm<128, 256><<<ngrid, 256, 0, stream>>>(h2, btf, fc1b, h3, n_nodes);
    k_fc2<<<(n_nodes + 255) / 256, 256, 0, stream>>>(h3, fc2w, fc2b, out, n_nodes);
}

// Round 4
// 339.563 us; speedup vs baseline: 4.0658x; 1.0915x over previous
//
#include <hip/hip_runtime.h>
#include <math.h>

#define F_IN 3
#define CH 32
#define HEADS 4
#define C1_OUT 64
#define C2_OUT 128
#define LIN 256
#define NCLS 25

typedef __attribute__((ext_vector_type(8))) short bf16x8;
typedef __attribute__((ext_vector_type(4))) float f32x4;

__device__ __forceinline__ float elu_f(float x) {
    return x > 0.f ? x : (__expf(x) - 1.f);
}

__device__ __forceinline__ unsigned short f2bf(float f) {
    union { float f; unsigned int u; } v; v.f = f;
    unsigned int u = v.u + 0x7fffu + ((v.u >> 16) & 1u);
    return (unsigned short)(u >> 16);
}

__device__ __forceinline__ float bf2f(unsigned short u) {
    union { unsigned int u; float f; } v; v.u = ((unsigned int)u) << 16;
    return v.f;
}

__device__ __forceinline__ void softmax4(const float* __restrict__ c,
                                         float& q0, float& q1, float& q2, float& q3) {
    float c0 = c[0], c1 = c[1], c2 = c[2], c3 = c[3];
    float mx = fmaxf(fmaxf(c0, c1), fmaxf(c2, c3));
    float e0 = __expf(c0 - mx), e1 = __expf(c1 - mx);
    float e2 = __expf(c2 - mx), e3 = __expf(c3 - mx);
    float inv = 1.f / (e0 + e1 + e2 + e3);
    q0 = e0 * inv; q1 = e1 * inv; q2 = e2 * inv; q3 = e3 * inv;
}

// edge attention: softmax over heads of (p_src - p_dst + c)
__device__ __forceinline__ float4 qedge(float4 ps, float4 pd,
                                        float c0, float c1, float c2, float c3) {
    float t0 = ps.x - pd.x + c0, t1 = ps.y - pd.y + c1;
    float t2 = ps.z - pd.z + c2, t3 = ps.w - pd.w + c3;
    float mx = fmaxf(fmaxf(t0, t1), fmaxf(t2, t3));
    float e0 = __expf(t0 - mx), e1 = __expf(t1 - mx);
    float e2 = __expf(t2 - mx), e3 = __expf(t3 - mx);
    float inv = 1.f / (e0 + e1 + e2 + e3);
    return make_float4(e0 * inv, e1 * inv, e2 * inv, e3 * inv);
}

// ---------------- fc0: h0 = elu(x @ W + b) -> bf16 -------------------------
__global__ void k_fc0(const float* __restrict__ x, const float* __restrict__ w,
                      const float* __restrict__ b, unsigned short* __restrict__ h0,
                      int n_nodes) {
    int gid = blockIdx.x * blockDim.x + threadIdx.x;
    if (gid >= n_nodes * CH) return;
    int n = gid >> 5, c = gid & 31;
    float acc = b[c];
#pragma unroll
    for (int i = 0; i < F_IN; ++i) acc += x[n * F_IN + i] * w[i * CH + c];
    h0[gid] = f2bf(elu_f(acc));
}

// ---------------- degree count (into cur) ----------------------------------
__global__ void k_deg(const int* __restrict__ dst, int* __restrict__ deg, int ne) {
    int e = blockIdx.x * blockDim.x + threadIdx.x;
    if (e < ne) atomicAdd(&deg[dst[e]], 1);
}

// ---------------- two-level exclusive scan ---------------------------------
#define SCAN_BS 1024
__global__ __launch_bounds__(SCAN_BS) void k_scan_a(
    const int* __restrict__ deg, int* __restrict__ offa,
    int* __restrict__ blksum, int n) {
    __shared__ int buf[SCAN_BS];
    int tid = threadIdx.x;
    int i = blockIdx.x * SCAN_BS + tid;
    int v = (i < n) ? deg[i] : 0;
    buf[tid] = v;
    __syncthreads();
    for (int s = 1; s < SCAN_BS; s <<= 1) {
        int t = (tid >= s) ? buf[tid - s] : 0;
        __syncthreads();
        buf[tid] += t;
        __syncthreads();
    }
    if (i < n) offa[i] = buf[tid] - v;
    if (tid == SCAN_BS - 1) blksum[blockIdx.x] = buf[tid];
}

__global__ void k_scan_b(int* __restrict__ blksum, int* __restrict__ offa,
                         int nblk, int n) {
    int tid = threadIdx.x;
    int orig = (tid < nblk) ? blksum[tid] : 0;
    int v = orig;
#pragma unroll
    for (int s = 1; s < 64; s <<= 1) {
        int t = __shfl_up(v, s, 64);
        if (tid >= s) v += t;
    }
    if (tid < nblk) blksum[tid] = v - orig;
    if (tid == nblk - 1) offa[n] = v;
}

__global__ void k_scan_c(int* __restrict__ offa, int* __restrict__ cur,
                         const int* __restrict__ blksum, int n) {
    int i = blockIdx.x * blockDim.x + threadIdx.x;
    if (i < n) {
        int o = offa[i] + blksum[i >> 10];
        offa[i] = o;
        cur[i] = o;
    }
}

// ---------------- scatter src into dst-sorted order ------------------------
__global__ void k_scatter(const int* __restrict__ eidx, int* __restrict__ cur,
                          int* __restrict__ ssrc, int ne) {
    int e = blockIdx.x * blockDim.x + threadIdx.x;
    if (e >= ne) return;
    int s = eidx[e], d = eidx[ne + e];
    int pos = atomicAdd(&cur[d], 1);
    ssrc[pos] = s;
}

// ---------------- per-node head projection p[n,h] = h[n] . u_h (bf16 in) ---
template<int IN>
__global__ void k_proj(const unsigned short* __restrict__ h,
                       const float* __restrict__ u,
                       float* __restrict__ p, int n_nodes) {
    int node = blockIdx.x * blockDim.x + threadIdx.x;
    if (node >= n_nodes) return;
    const unsigned short* hr = h + (size_t)node * IN;
    float a0 = 0.f, a1 = 0.f, a2 = 0.f, a3 = 0.f;
#pragma unroll
    for (int kb = 0; kb < IN; kb += 8) {
        uint4 uu = *(const uint4*)(hr + kb);
        unsigned int ws_[4] = {uu.x, uu.y, uu.z, uu.w};
#pragma unroll
        for (int j = 0; j < 4; ++j) {
            float vlo = bf2f((unsigned short)(ws_[j] & 0xffffu));
            float vhi = bf2f((unsigned short)(ws_[j] >> 16));
            int k0 = kb + j * 2, k1 = kb + j * 2 + 1;
            a0 = fmaf(vlo, u[k0 * HEADS + 0], a0); a0 = fmaf(vhi, u[k1 * HEADS + 0], a0);
            a1 = fmaf(vlo, u[k0 * HEADS + 1], a1); a1 = fmaf(vhi, u[k1 * HEADS + 1], a1);
            a2 = fmaf(vlo, u[k0 * HEADS + 2], a2); a2 = fmaf(vhi, u[k1 * HEADS + 2], a2);
            a3 = fmaf(vlo, u[k0 * HEADS + 3], a3); a3 = fmaf(vhi, u[k1 * HEADS + 3], a3);
        }
    }
    p[node * 4 + 0] = a0; p[node * 4 + 1] = a1;
    p[node * 4 + 2] = a2; p[node * 4 + 3] = a3;
}

// ---------------- conv1 gather-aggregate (fused q), bf16 in/out ------------
__global__ __launch_bounds__(256) void k_agg1(
    const unsigned short* __restrict__ h, const float* __restrict__ p,
    const int* __restrict__ offa, const int* __restrict__ ssrc,
    const float* __restrict__ cvec, unsigned short* __restrict__ arow,
    int n_nodes) {
    int wid = (blockIdx.x * blockDim.x + threadIdx.x) >> 6;
    int lane = threadIdx.x & 63;
    if (wid >= n_nodes) return;
    int half = lane >> 5, k = lane & 31;
    float c0 = cvec[0], c1 = cvec[1], c2 = cvec[2], c3 = cvec[3];
    const float4* pp = (const float4*)p;
    float4 pd = pp[wid];
    int e0 = offa[wid], e1 = offa[wid + 1];
    float a0 = 0.f, a1 = 0.f, a2 = 0.f, a3 = 0.f;
    int e = e0 + half;
    // 2 edges in flight per half (4 per wave)
    for (; e + 2 < e1; e += 4) {
        int sa = ssrc[e], sb = ssrc[e + 2];
        float4 psa = pp[sa], psb = pp[sb];
        float xa = bf2f(h[(size_t)sa * CH + k]);
        float xb = bf2f(h[(size_t)sb * CH + k]);
        float4 qa = qedge(psa, pd, c0, c1, c2, c3);
        float4 qb = qedge(psb, pd, c0, c1, c2, c3);
        a0 = fmaf(qa.x, xa, a0); a1 = fmaf(qa.y, xa, a1);
        a2 = fmaf(qa.z, xa, a2); a3 = fmaf(qa.w, xa, a3);
        a0 = fmaf(qb.x, xb, a0); a1 = fmaf(qb.y, xb, a1);
        a2 = fmaf(qb.z, xb, a2); a3 = fmaf(qb.w, xb, a3);
    }
    if (e < e1) {
        int sa = ssrc[e];
        float4 psa = pp[sa];
        float xa = bf2f(h[(size_t)sa * CH + k]);
        float4 qa = qedge(psa, pd, c0, c1, c2, c3);
        a0 = fmaf(qa.x, xa, a0); a1 = fmaf(qa.y, xa, a1);
        a2 = fmaf(qa.z, xa, a2); a3 = fmaf(qa.w, xa, a3);
    }
    a0 += __shfl_xor(a0, 32); a1 += __shfl_xor(a1, 32);
    a2 += __shfl_xor(a2, 32); a3 += __shfl_xor(a3, 32);
    if (half == 0) {
        float qc0, qc1, qc2, qc3;
        softmax4(cvec, qc0, qc1, qc2, qc3);
        float xi = bf2f(h[(size_t)wid * CH + k]);
        a0 = fmaf(qc0, xi, a0); a1 = fmaf(qc1, xi, a1);
        a2 = fmaf(qc2, xi, a2); a3 = fmaf(qc3, xi, a3);
        float inv = 1.f / (float)(e1 - e0 + 1);
        arow[(size_t)wid * 128 + 0 * CH + k] = f2bf(a0 * inv);
        arow[(size_t)wid * 128 + 1 * CH + k] = f2bf(a1 * inv);
        arow[(size_t)wid * 128 + 2 * CH + k] = f2bf(a2 * inv);
        arow[(size_t)wid * 128 + 3 * CH + k] = f2bf(a3 * inv);
    }
}

// ---------------- conv2 gather-aggregate (fused q), bf16 in/out ------------
__global__ __launch_bounds__(256) void k_agg2(
    const unsigned short* __restrict__ h, const float* __restrict__ p,
    const int* __restrict__ offa, const int* __restrict__ ssrc,
    const float* __restrict__ cvec, unsigned short* __restrict__ arow,
    int n_nodes) {
    int wid = (blockIdx.x * blockDim.x + threadIdx.x) >> 6;
    int lane = threadIdx.x & 63;
    if (wid >= n_nodes) return;
    float c0 = cvec[0], c1 = cvec[1], c2 = cvec[2], c3 = cvec[3];
    const float4* pp = (const float4*)p;
    float4 pd = pp[wid];
    int e0 = offa[wid], e1 = offa[wid + 1];
    float a0 = 0.f, a1 = 0.f, a2 = 0.f, a3 = 0.f;
    int e = e0;
    // 4 edges in flight
    for (; e + 3 < e1; e += 4) {
        int sa = ssrc[e], sb = ssrc[e + 1], sc = ssrc[e + 2], sd = ssrc[e + 3];
        float4 psa = pp[sa], psb = pp[sb], psc = pp[sc], psd = pp[sd];
        float xa = bf2f(h[(size_t)sa * C1_OUT + lane]);
        float xb = bf2f(h[(size_t)sb * C1_OUT + lane]);
        float xc = bf2f(h[(size_t)sc * C1_OUT + lane]);
        float xd = bf2f(h[(size_t)sd * C1_OUT + lane]);
        float4 qa = qedge(psa, pd, c0, c1, c2, c3);
        float4 qb = qedge(psb, pd, c0, c1, c2, c3);
        float4 qc = qedge(psc, pd, c0, c1, c2, c3);
        float4 qd = qedge(psd, pd, c0, c1, c2, c3);
        a0 = fmaf(qa.x, xa, a0); a1 = fmaf(qa.y, xa, a1);
        a2 = fmaf(qa.z, xa, a2); a3 = fmaf(qa.w, xa, a3);
        a0 = fmaf(qb.x, xb, a0); a1 = fmaf(qb.y, xb, a1);
        a2 = fmaf(qb.z, xb, a2); a3 = fmaf(qb.w, xb, a3);
        a0 = fmaf(qc.x, xc, a0); a1 = fmaf(qc.y, xc, a1);
        a2 = fmaf(qc.z, xc, a2); a3 = fmaf(qc.w, xc, a3);
        a0 = fmaf(qd.x, xd, a0); a1 = fmaf(qd.y, xd, a1);
        a2 = fmaf(qd.z, xd, a2); a3 = fmaf(qd.w, xd, a3);
    }
    for (; e < e1; ++e) {
        int sa = ssrc[e];
        float4 psa = pp[sa];
        float xa = bf2f(h[(size_t)sa * C1_OUT + lane]);
        float4 qa = qedge(psa, pd, c0, c1, c2, c3);
        a0 = fmaf(qa.x, xa, a0); a1 = fmaf(qa.y, xa, a1);
        a2 = fmaf(qa.z, xa, a2); a3 = fmaf(qa.w, xa, a3);
    }
    float qc0, qc1, qc2, qc3;
    softmax4(cvec, qc0, qc1, qc2, qc3);
    float xi = bf2f(h[(size_t)wid * C1_OUT + lane]);
    a0 = fmaf(qc0, xi, a0); a1 = fmaf(qc1, xi, a1);
    a2 = fmaf(qc2, xi, a2); a3 = fmaf(qc3, xi, a3);
    float inv = 1.f / (float)(e1 - e0 + 1);
    arow[(size_t)wid * 256 + 0 * C1_OUT + lane] = f2bf(a0 * inv);
    arow[(size_t)wid * 256 + 1 * C1_OUT + lane] = f2bf(a1 * inv);
    arow[(size_t)wid * 256 + 2 * C1_OUT + lane] = f2bf(a2 * inv);
    arow[(size_t)wid * 256 + 3 * C1_OUT + lane] = f2bf(a3 * inv);
}

// ---------------- weight prep: Bt[o*K + j] = bf16(remap(W)) ----------------
template<int K, int M, int IN>
__global__ void k_prepB(const float* __restrict__ W, unsigned short* __restrict__ Bt) {
    int idx = blockIdx.x * blockDim.x + threadIdx.x;
    if (idx >= K * M) return;
    int o = idx / K, j = idx % K;
    float v;
    if (IN > 0) {
        int hh = j / IN, k = j % IN;
        v = W[k * (HEADS * M) + hh * M + o];
    } else {
        v = W[j * M + o];
    }
    Bt[idx] = f2bf(v);
}

// ---------------- MFMA GEMM: D = bf16(elu(A @ Bt^T + bias)), A bf16 --------
template<int K, int M>
__global__ __launch_bounds__(256) void k_mgemm(
    const unsigned short* __restrict__ A, const unsigned short* __restrict__ Bt,
    const float* __restrict__ bias, unsigned short* __restrict__ D, int n) {
    constexpr int CPW = M / 4;
    constexpr int NCF = CPW / 16;
    constexpr int NKC = K / 32;
    __shared__ unsigned short Al[64 * K];
    int tid = threadIdx.x;
    int w = tid >> 6, l = tid & 63;
    int l16 = l & 15, l4 = l >> 4;
    int rowbase = blockIdx.x * 64;

    bf16x8 bfr[NCF][NKC];
#pragma unroll
    for (int c = 0; c < NCF; ++c)
#pragma unroll
        for (int t = 0; t < NKC; ++t) {
            int col = w * CPW + c * 16 + l16;
            int k = t * 32 + l4 * 8;
            bfr[c][t] = *(const bf16x8*)(Bt + (size_t)col * K + k);
        }

    // stage A tile (already bf16), XOR-swizzled rows
    constexpr int CHUNKS = 64 * K / 8;
    for (int idx = tid; idx < CHUNKS; idx += 256) {
        int row = idx / (K / 8);
        int kb = (idx % (K / 8)) * 8;
        int grow = rowbase + row;
        uint4 u;
        if (grow < n) u = *(const uint4*)(A + (size_t)grow * K + kb);
        else          u.x = u.y = u.z = u.w = 0u;
        int byte = ((row * K + kb) * 2) ^ ((row & 7) << 4);
        *(uint4*)((char*)Al + byte) = u;
    }
    __syncthreads();

#pragma unroll
    for (int r = 0; r < 4; ++r) {
        bf16x8 af[NKC];
        int row = r * 16 + l16;
#pragma unroll
        for (int t = 0; t < NKC; ++t) {
            int byte = ((row * K + t * 32 + l4 * 8) * 2) ^ ((row & 7) << 4);
            af[t] = *(bf16x8*)((char*)Al + byte);
        }
#pragma unroll
        for (int c = 0; c < NCF; ++c) {
            f32x4 acc = {0.f, 0.f, 0.f, 0.f};
#pragma unroll
            for (int t = 0; t < NKC; ++t)
                acc = __builtin_amdgcn_mfma_f32_16x16x32_bf16(af[t], bfr[c][t], acc, 0, 0, 0);
            int col = w * CPW + c * 16 + l16;
            float bv = bias[col];
#pragma unroll
            for (int j = 0; j < 4; ++j) {
                int grow = rowbase + r * 16 + l4 * 4 + j;
                if (grow < n)
                    D[(size_t)grow * M + col] = f2bf(elu_f(acc[j] + bv));
            }
        }
    }
}

// ---------------- fc2 + log_softmax (bf16 in, fp32 out) --------------------
__global__ void k_fc2(const unsigned short* __restrict__ h3,
                      const float* __restrict__ W,
                      const float* __restrict__ bias, float* __restrict__ out,
                      int n_nodes) {
    int n = blockIdx.x * blockDim.x + threadIdx.x;
    if (n >= n_nodes) return;
    float acc[NCLS];
#pragma unroll
    for (int o = 0; o < NCLS; ++o) acc[o] = bias[o];
    const unsigned short* xr = h3 + (size_t)n * LIN;
    for (int kb = 0; kb < LIN; kb += 8) {
        uint4 u = *(const uint4*)(xr + kb);
        unsigned int ws_[4] = {u.x, u.y, u.z, u.w};
#pragma unroll
        for (int j = 0; j < 4; ++j) {
            float vlo = bf2f((unsigned short)(ws_[j] & 0xffffu));
            float vhi = bf2f((unsigned short)(ws_[j] >> 16));
            const float* w0 = W + (kb + j * 2) * NCLS;
            const float* w1 = W + (kb + j * 2 + 1) * NCLS;
#pragma unroll
            for (int o = 0; o < NCLS; ++o) {
                acc[o] = fmaf(vlo, w0[o], acc[o]);
                acc[o] = fmaf(vhi, w1[o], acc[o]);
            }
        }
    }
    float mx = acc[0];
#pragma unroll
    for (int o = 1; o < NCLS; ++o) mx = fmaxf(mx, acc[o]);
    float sum = 0.f;
#pragma unroll
    for (int o = 0; o < NCLS; ++o) sum += __expf(acc[o] - mx);
    float lse = mx + __logf(sum);
#pragma unroll
    for (int o = 0; o < NCLS; ++o) out[(size_t)n * NCLS + o] = acc[o] - lse;
}

extern "C" void kernel_launch(void* const* d_in, const int* in_sizes, int n_in,
                              void* d_out, int out_size, void* d_ws, size_t ws_size,
                              hipStream_t stream) {
    const float* x     = (const float*)d_in[0];
    const int*   eidx  = (const int*)d_in[1];
    const float* fc0_w = (const float*)d_in[2];
    const float* fc0_b = (const float*)d_in[3];
    const float* c1w   = (const float*)d_in[4];
    const float* c1u   = (const float*)d_in[5];
    const float* c1c   = (const float*)d_in[6];
    const float* c1b   = (const float*)d_in[7];
    const float* c2w   = (const float*)d_in[8];
    const float* c2u   = (const float*)d_in[9];
    const float* c2c   = (const float*)d_in[10];
    const float* c2b   = (const float*)d_in[11];
    const float* fc1w  = (const float*)d_in[12];
    const float* fc1b  = (const float*)d_in[13];
    const float* fc2w  = (const float*)d_in[14];
    const float* fc2b  = (const float*)d_in[15];

    int n_nodes = in_sizes[0] / F_IN;   // 50000
    int ne      = in_sizes[1] / 2;      // 800000

    // ---- workspace layout (float units), liveness-aliased ----
    auto align4 = [](size_t v) { return (v + 3) & ~(size_t)3; };
    float* ws = (float*)d_ws;
    size_t t = 0;
    size_t off_o = t; t += align4((size_t)n_nodes + 1);
    size_t cur_o = t; t += align4((size_t)n_nodes);
    size_t blk_o = t; t += 64;
    size_t p_o   = t; t += align4((size_t)n_nodes * 4);
    size_t h1_o  = t; t += align4((size_t)n_nodes * 32);   // n*64 bf16
    size_t A_o   = t; t += align4((size_t)n_nodes * 128);  // arow1|arow2|h3 (n*256 bf16)
    size_t B_o   = t; t += align4((size_t)n_nodes * 64);   // {h0,ssrc} | h2
    size_t bt1_o = t; t += 4096;
    size_t bt2_o = t; t += 16384;
    size_t btf_o = t; t += 16384;

    size_t h0_o  = B_o;
    size_t ss_o  = align4(h0_o + (size_t)n_nodes * 16);    // h0 = n*32 bf16

    int*    offa   = (int*)(ws + off_o);
    int*    cur    = (int*)(ws + cur_o);
    int*    blksum = (int*)(ws + blk_o);
    float*  p      = ws + p_o;
    unsigned short* h1    = (unsigned short*)(ws + h1_o);
    unsigned short* arow1 = (unsigned short*)(ws + A_o);
    unsigned short* arow2 = (unsigned short*)(ws + A_o);
    unsigned short* h3    = (unsigned short*)(ws + A_o);
    unsigned short* h0    = (unsigned short*)(ws + h0_o);
    int*    ssrc   = (int*)(ws + ss_o);
    unsigned short* h2    = (unsigned short*)(ws + B_o);
    unsigned short* bt1 = (unsigned short*)(ws + bt1_o);
    unsigned short* bt2 = (unsigned short*)(ws + bt2_o);
    unsigned short* btf = (unsigned short*)(ws + btf_o);
    float*  out    = (float*)d_out;

    int nblk = (n_nodes + SCAN_BS - 1) / SCAN_BS;

    hipMemsetAsync(cur, 0, (size_t)n_nodes * sizeof(int), stream);

    k_prepB<128, 64, 32><<<(128 * 64 + 255) / 256, 256, 0, stream>>>(c1w, bt1);
    k_prepB<256, 128, 64><<<(256 * 128 + 255) / 256, 256, 0, stream>>>(c2w, bt2);
    k_prepB<128, 256, 0><<<(128 * 256 + 255) / 256, 256, 0, stream>>>(fc1w, btf);

    k_fc0<<<(n_nodes * CH + 255) / 256, 256, 0, stream>>>(x, fc0_w, fc0_b, h0, n_nodes);
    k_deg<<<(ne + 255) / 256, 256, 0, stream>>>(eidx + ne, cur, ne);
    k_scan_a<<<nblk, SCAN_BS, 0, stream>>>(cur, offa, blksum, n_nodes);
    k_scan_b<<<1, 64, 0, stream>>>(blksum, offa, nblk, n_nodes);
    k_scan_c<<<(n_nodes + 255) / 256, 256, 0, stream>>>(offa, cur, blksum, n_nodes);
    k_scatter<<<(ne + 255) / 256, 256, 0, stream>>>(eidx, cur, ssrc, ne);

    int ngrid = (n_nodes + 63) / 64;

    // conv1
    k_proj<CH><<<(n_nodes + 255) / 256, 256, 0, stream>>>(h0, c1u, p, n_nodes);
    k_agg1<<<(n_nodes * 64 + 255) / 256, 256, 0, stream>>>(h0, p, offa, ssrc, c1c, arow1, n_nodes);
    k_mgemm<128, 64><<<ngrid, 256, 0, stream>>>(arow1, bt1, c1b, h1, n_nodes);

    // conv2
    k_proj<C1_OUT><<<(n_nodes + 255) / 256, 256, 0, stream>>>(h1, c2u, p, n_nodes);
    k_agg2<<<(n_nodes * 64 + 255) / 256, 256, 0, stream>>>(h1, p, offa, ssrc, c2c, arow2, n_nodes);
    k_mgemm<256, 128><<<ngrid, 256, 0, stream>>>(arow2, bt2, c2b, h2, n_nodes);

    // head
    k_mgemm<128, 256><<<ngrid, 256, 0, stream>>>(h2, btf, fc1b, h3, n_nodes);
    k_fc2<<<(n_nodes + 255) / 256, 256, 0, stream>>>(h3, fc2w, fc2b, out, n_nodes);
}

// Round 5
// 319.152 us; speedup vs baseline: 4.3259x; 1.0640x over previous
//
#include <hip/hip_runtime.h>
#include <math.h>

#define F_IN 3
#define CH 32
#define HEADS 4
#define C1_OUT 64
#define C2_OUT 128
#define LIN 256
#define NCLS 25

typedef __attribute__((ext_vector_type(8))) short bf16x8;
typedef __attribute__((ext_vector_type(4))) float f32x4;

__device__ __forceinline__ float elu_f(float x) {
    return x > 0.f ? x : (__expf(x) - 1.f);
}

__device__ __forceinline__ unsigned short f2bf(float f) {
    union { float f; unsigned int u; } v; v.f = f;
    unsigned int u = v.u + 0x7fffu + ((v.u >> 16) & 1u);
    return (unsigned short)(u >> 16);
}

__device__ __forceinline__ float bf2f(unsigned short u) {
    union { unsigned int u; float f; } v; v.u = ((unsigned int)u) << 16;
    return v.f;
}

__device__ __forceinline__ void softmax4(const float* __restrict__ c,
                                         float& q0, float& q1, float& q2, float& q3) {
    float c0 = c[0], c1 = c[1], c2 = c[2], c3 = c[3];
    float mx = fmaxf(fmaxf(c0, c1), fmaxf(c2, c3));
    float e0 = __expf(c0 - mx), e1 = __expf(c1 - mx);
    float e2 = __expf(c2 - mx), e3 = __expf(c3 - mx);
    float inv = 1.f / (e0 + e1 + e2 + e3);
    q0 = e0 * inv; q1 = e1 * inv; q2 = e2 * inv; q3 = e3 * inv;
}

// ---------------- fc0: h0 = elu(x @ W + b) -> bf16 -------------------------
__global__ void k_fc0(const float* __restrict__ x, const float* __restrict__ w,
                      const float* __restrict__ b, unsigned short* __restrict__ h0,
                      int n_nodes) {
    int gid = blockIdx.x * blockDim.x + threadIdx.x;
    if (gid >= n_nodes * CH) return;
    int n = gid >> 5, c = gid & 31;
    float acc = b[c];
#pragma unroll
    for (int i = 0; i < F_IN; ++i) acc += x[n * F_IN + i] * w[i * CH + c];
    h0[gid] = f2bf(elu_f(acc));
}

// ---------------- degree count (into cur) ----------------------------------
__global__ void k_deg(const int* __restrict__ dst, int* __restrict__ deg, int ne) {
    int e = blockIdx.x * blockDim.x + threadIdx.x;
    if (e < ne) atomicAdd(&deg[dst[e]], 1);
}

// ---------------- two-level exclusive scan ---------------------------------
#define SCAN_BS 1024
__global__ __launch_bounds__(SCAN_BS) void k_scan_a(
    const int* __restrict__ deg, int* __restrict__ offa,
    int* __restrict__ blksum, int n) {
    __shared__ int buf[SCAN_BS];
    int tid = threadIdx.x;
    int i = blockIdx.x * SCAN_BS + tid;
    int v = (i < n) ? deg[i] : 0;
    buf[tid] = v;
    __syncthreads();
    for (int s = 1; s < SCAN_BS; s <<= 1) {
        int t = (tid >= s) ? buf[tid - s] : 0;
        __syncthreads();
        buf[tid] += t;
        __syncthreads();
    }
    if (i < n) offa[i] = buf[tid] - v;
    if (tid == SCAN_BS - 1) blksum[blockIdx.x] = buf[tid];
}

__global__ void k_scan_b(int* __restrict__ blksum, int* __restrict__ offa,
                         int nblk, int n) {
    int tid = threadIdx.x;
    int orig = (tid < nblk) ? blksum[tid] : 0;
    int v = orig;
#pragma unroll
    for (int s = 1; s < 64; s <<= 1) {
        int t = __shfl_up(v, s, 64);
        if (tid >= s) v += t;
    }
    if (tid < nblk) blksum[tid] = v - orig;
    if (tid == nblk - 1) offa[n] = v;
}

__global__ void k_scan_c(int* __restrict__ offa, int* __restrict__ cur,
                         const int* __restrict__ blksum, int n) {
    int i = blockIdx.x * blockDim.x + threadIdx.x;
    if (i < n) {
        int o = offa[i] + blksum[i >> 10];
        offa[i] = o;
        cur[i] = o;
    }
}

// ---------------- scatter edges into dst-sorted order ----------------------
__global__ void k_scatter(const int* __restrict__ eidx, int* __restrict__ cur,
                          int* __restrict__ ssrc, int* __restrict__ sdst, int ne) {
    int e = blockIdx.x * blockDim.x + threadIdx.x;
    if (e >= ne) return;
    int s = eidx[e], d = eidx[ne + e];
    int pos = atomicAdd(&cur[d], 1);
    ssrc[pos] = s;
    sdst[pos] = d;
}

// ---------------- per-node head projection p[n,h] = h[n] . u_h (bf16 in) ---
template<int IN>
__global__ void k_proj(const unsigned short* __restrict__ h,
                       const float* __restrict__ u,
                       float* __restrict__ p, int n_nodes) {
    int node = blockIdx.x * blockDim.x + threadIdx.x;
    if (node >= n_nodes) return;
    const unsigned short* hr = h + (size_t)node * IN;
    float a0 = 0.f, a1 = 0.f, a2 = 0.f, a3 = 0.f;
#pragma unroll
    for (int kb = 0; kb < IN; kb += 8) {
        uint4 uu = *(const uint4*)(hr + kb);
        unsigned int ws_[4] = {uu.x, uu.y, uu.z, uu.w};
#pragma unroll
        for (int j = 0; j < 4; ++j) {
            float vlo = bf2f((unsigned short)(ws_[j] & 0xffffu));
            float vhi = bf2f((unsigned short)(ws_[j] >> 16));
            int k0 = kb + j * 2, k1 = kb + j * 2 + 1;
            a0 = fmaf(vlo, u[k0 * HEADS + 0], a0); a0 = fmaf(vhi, u[k1 * HEADS + 0], a0);
            a1 = fmaf(vlo, u[k0 * HEADS + 1], a1); a1 = fmaf(vhi, u[k1 * HEADS + 1], a1);
            a2 = fmaf(vlo, u[k0 * HEADS + 2], a2); a2 = fmaf(vhi, u[k1 * HEADS + 2], a2);
            a3 = fmaf(vlo, u[k0 * HEADS + 3], a3); a3 = fmaf(vhi, u[k1 * HEADS + 3], a3);
        }
    }
    p[node * 4 + 0] = a0; p[node * 4 + 1] = a1;
    p[node * 4 + 2] = a2; p[node * 4 + 3] = a3;
}

// ---------------- per-edge attention weights (sorted order) ----------------
__global__ void k_q(const float* __restrict__ p, const float* __restrict__ cvec,
                    const int* __restrict__ ssrc, const int* __restrict__ sdst,
                    float4* __restrict__ q4, int ne) {
    int e = blockIdx.x * blockDim.x + threadIdx.x;
    if (e >= ne) return;
    int s = ssrc[e], d = sdst[e];
    const float4* pp = (const float4*)p;
    float4 ps = pp[s], pd = pp[d];
    float t0 = ps.x - pd.x + cvec[0];
    float t1 = ps.y - pd.y + cvec[1];
    float t2 = ps.z - pd.z + cvec[2];
    float t3 = ps.w - pd.w + cvec[3];
    float mx = fmaxf(fmaxf(t0, t1), fmaxf(t2, t3));
    float e0 = __expf(t0 - mx), e1 = __expf(t1 - mx);
    float e2 = __expf(t2 - mx), e3 = __expf(t3 - mx);
    float inv = 1.f / (e0 + e1 + e2 + e3);
    q4[e] = make_float4(e0 * inv, e1 * inv, e2 * inv, e3 * inv);
}

// ---------------- conv1 gather-aggregate, bf16 in/out ----------------------
__global__ __launch_bounds__(256) void k_agg1(
    const unsigned short* __restrict__ h, const int* __restrict__ offa,
    const int* __restrict__ ssrc, const float4* __restrict__ q4,
    const float* __restrict__ cvec, unsigned short* __restrict__ arow,
    int n_nodes) {
    int wid = (blockIdx.x * blockDim.x + threadIdx.x) >> 6;
    int lane = threadIdx.x & 63;
    if (wid >= n_nodes) return;
    int half = lane >> 5, k = lane & 31;
    int e0 = offa[wid], e1 = offa[wid + 1];
    float a0 = 0.f, a1 = 0.f, a2 = 0.f, a3 = 0.f;
    int e = e0 + half;
    // 2 edges in flight per half (4 per wave)
    for (; e + 2 < e1; e += 4) {
        int sa = ssrc[e], sb = ssrc[e + 2];
        float4 qa = q4[e], qb = q4[e + 2];
        float xa = bf2f(h[(size_t)sa * CH + k]);
        float xb = bf2f(h[(size_t)sb * CH + k]);
        a0 = fmaf(qa.x, xa, a0); a1 = fmaf(qa.y, xa, a1);
        a2 = fmaf(qa.z, xa, a2); a3 = fmaf(qa.w, xa, a3);
        a0 = fmaf(qb.x, xb, a0); a1 = fmaf(qb.y, xb, a1);
        a2 = fmaf(qb.z, xb, a2); a3 = fmaf(qb.w, xb, a3);
    }
    if (e < e1) {
        int sa = ssrc[e];
        float4 qa = q4[e];
        float xa = bf2f(h[(size_t)sa * CH + k]);
        a0 = fmaf(qa.x, xa, a0); a1 = fmaf(qa.y, xa, a1);
        a2 = fmaf(qa.z, xa, a2); a3 = fmaf(qa.w, xa, a3);
    }
    a0 += __shfl_xor(a0, 32); a1 += __shfl_xor(a1, 32);
    a2 += __shfl_xor(a2, 32); a3 += __shfl_xor(a3, 32);
    if (half == 0) {
        float qc0, qc1, qc2, qc3;
        softmax4(cvec, qc0, qc1, qc2, qc3);
        float xi = bf2f(h[(size_t)wid * CH + k]);
        a0 = fmaf(qc0, xi, a0); a1 = fmaf(qc1, xi, a1);
        a2 = fmaf(qc2, xi, a2); a3 = fmaf(qc3, xi, a3);
        float inv = 1.f / (float)(e1 - e0 + 1);
        arow[(size_t)wid * 128 + 0 * CH + k] = f2bf(a0 * inv);
        arow[(size_t)wid * 128 + 1 * CH + k] = f2bf(a1 * inv);
        arow[(size_t)wid * 128 + 2 * CH + k] = f2bf(a2 * inv);
        arow[(size_t)wid * 128 + 3 * CH + k] = f2bf(a3 * inv);
    }
}

// ---------------- conv2 gather-aggregate, bf16 in/out ----------------------
__global__ __launch_bounds__(256) void k_agg2(
    const unsigned short* __restrict__ h, const int* __restrict__ offa,
    const int* __restrict__ ssrc, const float4* __restrict__ q4,
    const float* __restrict__ cvec, unsigned short* __restrict__ arow,
    int n_nodes) {
    int wid = (blockIdx.x * blockDim.x + threadIdx.x) >> 6;
    int lane = threadIdx.x & 63;
    if (wid >= n_nodes) return;
    int e0 = offa[wid], e1 = offa[wid + 1];
    float a0 = 0.f, a1 = 0.f, a2 = 0.f, a3 = 0.f;
    int e = e0;
    // 4 edges in flight
    for (; e + 3 < e1; e += 4) {
        int sa = ssrc[e], sb = ssrc[e + 1], sc = ssrc[e + 2], sd = ssrc[e + 3];
        float4 qa = q4[e], qb = q4[e + 1], qc = q4[e + 2], qd = q4[e + 3];
        float xa = bf2f(h[(size_t)sa * C1_OUT + lane]);
        float xb = bf2f(h[(size_t)sb * C1_OUT + lane]);
        float xc = bf2f(h[(size_t)sc * C1_OUT + lane]);
        float xd = bf2f(h[(size_t)sd * C1_OUT + lane]);
        a0 = fmaf(qa.x, xa, a0); a1 = fmaf(qa.y, xa, a1);
        a2 = fmaf(qa.z, xa, a2); a3 = fmaf(qa.w, xa, a3);
        a0 = fmaf(qb.x, xb, a0); a1 = fmaf(qb.y, xb, a1);
        a2 = fmaf(qb.z, xb, a2); a3 = fmaf(qb.w, xb, a3);
        a0 = fmaf(qc.x, xc, a0); a1 = fmaf(qc.y, xc, a1);
        a2 = fmaf(qc.z, xc, a2); a3 = fmaf(qc.w, xc, a3);
        a0 = fmaf(qd.x, xd, a0); a1 = fmaf(qd.y, xd, a1);
        a2 = fmaf(qd.z, xd, a2); a3 = fmaf(qd.w, xd, a3);
    }
    for (; e < e1; ++e) {
        int sa = ssrc[e];
        float4 qa = q4[e];
        float xa = bf2f(h[(size_t)sa * C1_OUT + lane]);
        a0 = fmaf(qa.x, xa, a0); a1 = fmaf(qa.y, xa, a1);
        a2 = fmaf(qa.z, xa, a2); a3 = fmaf(qa.w, xa, a3);
    }
    float qc0, qc1, qc2, qc3;
    softmax4(cvec, qc0, qc1, qc2, qc3);
    float xi = bf2f(h[(size_t)wid * C1_OUT + lane]);
    a0 = fmaf(qc0, xi, a0); a1 = fmaf(qc1, xi, a1);
    a2 = fmaf(qc2, xi, a2); a3 = fmaf(qc3, xi, a3);
    float inv = 1.f / (float)(e1 - e0 + 1);
    arow[(size_t)wid * 256 + 0 * C1_OUT + lane] = f2bf(a0 * inv);
    arow[(size_t)wid * 256 + 1 * C1_OUT + lane] = f2bf(a1 * inv);
    arow[(size_t)wid * 256 + 2 * C1_OUT + lane] = f2bf(a2 * inv);
    arow[(size_t)wid * 256 + 3 * C1_OUT + lane] = f2bf(a3 * inv);
}

// ---------------- weight prep: Bt[o*K + j] = bf16(remap(W)) ----------------
template<int K, int M, int IN>
__global__ void k_prepB(const float* __restrict__ W, unsigned short* __restrict__ Bt) {
    int idx = blockIdx.x * blockDim.x + threadIdx.x;
    if (idx >= K * M) return;
    int o = idx / K, j = idx % K;
    float v;
    if (IN > 0) {
        int hh = j / IN, k = j % IN;
        v = W[k * (HEADS * M) + hh * M + o];
    } else {
        v = W[j * M + o];
    }
    Bt[idx] = f2bf(v);
}

// ---------------- MFMA GEMM: D = bf16(elu(A @ Bt^T + bias)), A bf16 --------
template<int K, int M>
__global__ __launch_bounds__(256) void k_mgemm(
    const unsigned short* __restrict__ A, const unsigned short* __restrict__ Bt,
    const float* __restrict__ bias, unsigned short* __restrict__ D, int n) {
    constexpr int CPW = M / 4;
    constexpr int NCF = CPW / 16;
    constexpr int NKC = K / 32;
    __shared__ unsigned short Al[64 * K];
    int tid = threadIdx.x;
    int w = tid >> 6, l = tid & 63;
    int l16 = l & 15, l4 = l >> 4;
    int rowbase = blockIdx.x * 64;

    bf16x8 bfr[NCF][NKC];
#pragma unroll
    for (int c = 0; c < NCF; ++c)
#pragma unroll
        for (int t = 0; t < NKC; ++t) {
            int col = w * CPW + c * 16 + l16;
            int k = t * 32 + l4 * 8;
            bfr[c][t] = *(const bf16x8*)(Bt + (size_t)col * K + k);
        }

    // stage A tile (already bf16), XOR-swizzled rows
    constexpr int CHUNKS = 64 * K / 8;
    for (int idx = tid; idx < CHUNKS; idx += 256) {
        int row = idx / (K / 8);
        int kb = (idx % (K / 8)) * 8;
        int grow = rowbase + row;
        uint4 u;
        if (grow < n) u = *(const uint4*)(A + (size_t)grow * K + kb);
        else          u.x = u.y = u.z = u.w = 0u;
        int byte = ((row * K + kb) * 2) ^ ((row & 7) << 4);
        *(uint4*)((char*)Al + byte) = u;
    }
    __syncthreads();

#pragma unroll
    for (int r = 0; r < 4; ++r) {
        bf16x8 af[NKC];
        int row = r * 16 + l16;
#pragma unroll
        for (int t = 0; t < NKC; ++t) {
            int byte = ((row * K + t * 32 + l4 * 8) * 2) ^ ((row & 7) << 4);
            af[t] = *(bf16x8*)((char*)Al + byte);
        }
#pragma unroll
        for (int c = 0; c < NCF; ++c) {
            f32x4 acc = {0.f, 0.f, 0.f, 0.f};
#pragma unroll
            for (int t = 0; t < NKC; ++t)
                acc = __builtin_amdgcn_mfma_f32_16x16x32_bf16(af[t], bfr[c][t], acc, 0, 0, 0);
            int col = w * CPW + c * 16 + l16;
            float bv = bias[col];
#pragma unroll
            for (int j = 0; j < 4; ++j) {
                int grow = rowbase + r * 16 + l4 * 4 + j;
                if (grow < n)
                    D[(size_t)grow * M + col] = f2bf(elu_f(acc[j] + bv));
            }
        }
    }
}

// ---------------- fc2 + log_softmax (bf16 in, fp32 out) --------------------
__global__ void k_fc2(const unsigned short* __restrict__ h3,
                      const float* __restrict__ W,
                      const float* __restrict__ bias, float* __restrict__ out,
                      int n_nodes) {
    int n = blockIdx.x * blockDim.x + threadIdx.x;
    if (n >= n_nodes) return;
    float acc[NCLS];
#pragma unroll
    for (int o = 0; o < NCLS; ++o) acc[o] = bias[o];
    const unsigned short* xr = h3 + (size_t)n * LIN;
    for (int kb = 0; kb < LIN; kb += 8) {
        uint4 u = *(const uint4*)(xr + kb);
        unsigned int ws_[4] = {u.x, u.y, u.z, u.w};
#pragma unroll
        for (int j = 0; j < 4; ++j) {
            float vlo = bf2f((unsigned short)(ws_[j] & 0xffffu));
            float vhi = bf2f((unsigned short)(ws_[j] >> 16));
            const float* w0 = W + (kb + j * 2) * NCLS;
            const float* w1 = W + (kb + j * 2 + 1) * NCLS;
#pragma unroll
            for (int o = 0; o < NCLS; ++o) {
                acc[o] = fmaf(vlo, w0[o], acc[o]);
                acc[o] = fmaf(vhi, w1[o], acc[o]);
            }
        }
    }
    float mx = acc[0];
#pragma unroll
    for (int o = 1; o < NCLS; ++o) mx = fmaxf(mx, acc[o]);
    float sum = 0.f;
#pragma unroll
    for (int o = 0; o < NCLS; ++o) sum += __expf(acc[o] - mx);
    float lse = mx + __logf(sum);
#pragma unroll
    for (int o = 0; o < NCLS; ++o) out[(size_t)n * NCLS + o] = acc[o] - lse;
}

extern "C" void kernel_launch(void* const* d_in, const int* in_sizes, int n_in,
                              void* d_out, int out_size, void* d_ws, size_t ws_size,
                              hipStream_t stream) {
    const float* x     = (const float*)d_in[0];
    const int*   eidx  = (const int*)d_in[1];
    const float* fc0_w = (const float*)d_in[2];
    const float* fc0_b = (const float*)d_in[3];
    const float* c1w   = (const float*)d_in[4];
    const float* c1u   = (const float*)d_in[5];
    const float* c1c   = (const float*)d_in[6];
    const float* c1b   = (const float*)d_in[7];
    const float* c2w   = (const float*)d_in[8];
    const float* c2u   = (const float*)d_in[9];
    const float* c2c   = (const float*)d_in[10];
    const float* c2b   = (const float*)d_in[11];
    const float* fc1w  = (const float*)d_in[12];
    const float* fc1b  = (const float*)d_in[13];
    const float* fc2w  = (const float*)d_in[14];
    const float* fc2b  = (const float*)d_in[15];

    int n_nodes = in_sizes[0] / F_IN;   // 50000
    int ne      = in_sizes[1] / 2;      // 800000

    // ---- workspace layout (float units), liveness-aliased ----
    auto align4 = [](size_t v) { return (v + 3) & ~(size_t)3; };
    float* ws = (float*)d_ws;
    size_t t = 0;
    size_t off_o = t; t += align4((size_t)n_nodes + 1);
    size_t cur_o = t; t += align4((size_t)n_nodes);
    size_t blk_o = t; t += 64;
    size_t p_o   = t; t += align4((size_t)n_nodes * 4);
    size_t h1_o  = t; t += align4((size_t)n_nodes * 32);   // n*64 bf16
    size_t A_o   = t; t += align4((size_t)n_nodes * 128);  // arow1|arow2|h3 (n*256 bf16)
    // B region: {h0, ssrc, sdst, q4} early | h2 late
    size_t B_o   = t;
    size_t h0_o  = B_o;                                    // n*32 bf16 = 16n fl
    size_t ss_o  = align4(h0_o + (size_t)n_nodes * 16);
    size_t sd_o  = align4(ss_o + (size_t)ne);
    size_t q4_o  = align4(sd_o + (size_t)ne);
    size_t B_end = q4_o + (size_t)ne * 4;
    size_t B_sz  = B_end - B_o;
    size_t h2_sz = (size_t)n_nodes * 64;                   // n*128 bf16
    t = B_o + (B_sz > h2_sz ? B_sz : h2_sz);
    size_t bt1_o = t; t += 4096;
    size_t bt2_o = t; t += 16384;
    size_t btf_o = t; t += 16384;

    int*    offa   = (int*)(ws + off_o);
    int*    cur    = (int*)(ws + cur_o);
    int*    blksum = (int*)(ws + blk_o);
    float*  p      = ws + p_o;
    unsigned short* h1    = (unsigned short*)(ws + h1_o);
    unsigned short* arow1 = (unsigned short*)(ws + A_o);
    unsigned short* arow2 = (unsigned short*)(ws + A_o);
    unsigned short* h3    = (unsigned short*)(ws + A_o);
    unsigned short* h0    = (unsigned short*)(ws + h0_o);
    int*    ssrc   = (int*)(ws + ss_o);
    int*    sdst   = (int*)(ws + sd_o);
    float4* q4     = (float4*)(ws + q4_o);
    unsigned short* h2    = (unsigned short*)(ws + B_o);   // after ssrc/sdst/q4 dead
    unsigned short* bt1 = (unsigned short*)(ws + bt1_o);
    unsigned short* bt2 = (unsigned short*)(ws + bt2_o);
    unsigned short* btf = (unsigned short*)(ws + btf_o);
    float*  out    = (float*)d_out;

    int nblk = (n_nodes + SCAN_BS - 1) / SCAN_BS;

    hipMemsetAsync(cur, 0, (size_t)n_nodes * sizeof(int), stream);

    k_prepB<128, 64, 32><<<(128 * 64 + 255) / 256, 256, 0, stream>>>(c1w, bt1);
    k_prepB<256, 128, 64><<<(256 * 128 + 255) / 256, 256, 0, stream>>>(c2w, bt2);
    k_prepB<128, 256, 0><<<(128 * 256 + 255) / 256, 256, 0, stream>>>(fc1w, btf);

    k_fc0<<<(n_nodes * CH + 255) / 256, 256, 0, stream>>>(x, fc0_w, fc0_b, h0, n_nodes);
    k_deg<<<(ne + 255) / 256, 256, 0, stream>>>(eidx + ne, cur, ne);
    k_scan_a<<<nblk, SCAN_BS, 0, stream>>>(cur, offa, blksum, n_nodes);
    k_scan_b<<<1, 64, 0, stream>>>(blksum, offa, nblk, n_nodes);
    k_scan_c<<<(n_nodes + 255) / 256, 256, 0, stream>>>(offa, cur, blksum, n_nodes);
    k_scatter<<<(ne + 255) / 256, 256, 0, stream>>>(eidx, cur, ssrc, sdst, ne);

    int ngrid = (n_nodes + 63) / 64;

    // conv1
    k_proj<CH><<<(n_nodes + 255) / 256, 256, 0, stream>>>(h0, c1u, p, n_nodes);
    k_q<<<(ne + 255) / 256, 256, 0, stream>>>(p, c1c, ssrc, sdst, q4, ne);
    k_agg1<<<(n_nodes * 64 + 255) / 256, 256, 0, stream>>>(h0, offa, ssrc, q4, c1c, arow1, n_nodes);
    k_mgemm<128, 64><<<ngrid, 256, 0, stream>>>(arow1, bt1, c1b, h1, n_nodes);

    // conv2
    k_proj<C1_OUT><<<(n_nodes + 255) / 256, 256, 0, stream>>>(h1, c2u, p, n_nodes);
    k_q<<<(ne + 255) / 256, 256, 0, stream>>>(p, c2c, ssrc, sdst, q4, ne);
    k_agg2<<<(n_nodes * 64 + 255) / 256, 256, 0, stream>>>(h1, offa, ssrc, q4, c2c, arow2, n_nodes);
    k_mgemm<256, 128><<<ngrid, 256, 0, stream>>>(arow2, bt2, c2b, h2, n_nodes);

    // head
    k_mgemm<128, 256><<<ngrid, 256, 0, stream>>>(h2, btf, fc1b, h3, n_nodes);
    k_fc2<<<(n_nodes + 255) / 256, 256, 0, stream>>>(h3, fc2w, fc2b, out, n_nodes);
}